// Round 15
// baseline (2703.896 us; speedup 1.0000x reference)
//
#include <hip/hip_runtime.h>
#include <hip/hip_fp16.h>
#include <math.h>

// ---------------------------------------------------------------------------
// RelationExtractionModel B=64,T=256. Round 24: k_tree_tail — the last 5
// tree stages (plo 8,4,2,1,0; 10 tiny dependent launches that were ~pure
// dispatch latency) collapsed into ONE batch-local kernel (64 blocks, H/C
// rows <32 in LDS, fp32 VALU dots, epilogue formulas verbatim from the
// proven k_tgemm-epi2/k_update). Stages 0-2 (real GEMM work) keep the
// proven MFMA path. Everything else = round 23 (1624us verified:
// thin-slice LSTM 868us, busy-poll, xW prefetch, merged launches).
// ---------------------------------------------------------------------------

typedef _Float16 f16x8 __attribute__((ext_vector_type(8)));
typedef _Float16 f16x4 __attribute__((ext_vector_type(4)));
typedef float    f32x4 __attribute__((ext_vector_type(4)));

union PK { _Float16 h[8]; unsigned long long u64[2]; f16x8 v; };
union PK4 { _Float16 h[4]; unsigned long long u64; f16x4 v; };

#define LOG2E 1.44269504088896340736f

__device__ __forceinline__ float fexp2(float x) {
  return __builtin_amdgcn_exp2f(x);
}
__device__ __forceinline__ float frcp(float x) {
  return __builtin_amdgcn_rcpf(x);
}
__device__ __forceinline__ float sigm(float x) {
  return frcp(1.0f + fexp2(-LOG2E * x));
}
__device__ __forceinline__ float tanh_fast(float x) {
  return 1.0f - 2.0f * frcp(1.0f + fexp2(2.0f * LOG2E * x));
}

struct EmbArgs {
  const float* tf; const int* pos_ids; const int* dep_ids;
  const int* e1; const int* e2; const int* sdp;
  const float* pos_tab; const float* dep_tab; const float* dist_tab;
  const float* sdp_tab;
};

// ---------------- merged prep: packs + zft + WB packs + flag zero + depfill
// ranges (all multiples of 256; formulas verbatim from proven kernels):
//  BTft 466944 | zft 8192 | BTwhf 524288 | BTwhb 524288 | BTiou 417792 |
//  BTf 139264 | WBf 262144 | WBb 262144 | FLG 8192 | depfill 524288 |
//  BTuf 65536 | BTuiou 196608   -> total 3399680 = 13280 blocks x 256
__global__ __launch_bounds__(256) void k_prep(
    const float* __restrict__ W_ft, __half* __restrict__ BTft,
    const float* __restrict__ Wih_f, __half* __restrict__ BTwhf,
    const float* __restrict__ Wih_b, __half* __restrict__ BTwhb,
    const float* __restrict__ W_iou, __half* __restrict__ BTiou,
    const float* __restrict__ Wf_t, __half* __restrict__ BTf,
    const float* __restrict__ Whh_f, __half* __restrict__ WBf,
    const float* __restrict__ Whh_b, __half* __restrict__ WBb,
    unsigned int* __restrict__ FLG,
    const int* __restrict__ dep_ids, const float* __restrict__ dep_tab,
    __half* __restrict__ XT,
    const float* __restrict__ Uf, __half* __restrict__ BTuf,
    const float* __restrict__ Uiou, __half* __restrict__ BTuiou) {
  int e = blockIdx.x * 256 + threadIdx.x;
  if (e < 466944) {                       // BTft: n fastest (coalesced read)
    int n = e & 511, k = e >> 9;          // k<912
    BTft[(size_t)n * 928 + k] = __float2half_rn(W_ft[(size_t)k * 512 + n]);
  } else if ((e -= 466944) < 8192) {      // zft pad cols [912,928)
    int n = e >> 4, kk = e & 15;
    BTft[(size_t)n * 928 + 912 + kk] = __float2half_rn(0.0f);
  } else if ((e -= 8192) < 524288) {      // BTwhf
    int n = e & 1023, k = e >> 10;        // k<512
    BTwhf[(size_t)n * 512 + k] = __float2half_rn(Wih_f[(size_t)k * 1024 + n]);
  } else if ((e -= 524288) < 524288) {    // BTwhb
    int n = e & 1023, k = e >> 10;
    BTwhb[(size_t)n * 512 + k] = __float2half_rn(Wih_b[(size_t)k * 1024 + n]);
  } else if ((e -= 524288) < 417792) {    // BTiou: N=768, K=544
    int n = e % 768, k = e / 768;
    BTiou[(size_t)n * 544 + k] = __float2half_rn(W_iou[(size_t)k * 768 + n]);
  } else if ((e -= 417792) < 139264) {    // BTf: N=256, K=544
    int n = e & 255, k = e >> 8;
    BTf[(size_t)n * 544 + k] = __float2half_rn(Wf_t[(size_t)k * 256 + n]);
  } else if ((e -= 139264) < 262144) {    // WBf  [r11 k_packWB verbatim]
    int k = e & 255, c = (e >> 8) & 127, j = e >> 15;
    int col = (c & 3) * 256 + j * 32 + (c >> 2);
    WBf[e] = __float2half_rn(Whh_f[(size_t)k * 1024 + col]);
  } else if ((e -= 262144) < 262144) {    // WBb
    int k = e & 255, c = (e >> 8) & 127, j = e >> 15;
    int col = (c & 3) * 256 + j * 32 + (c >> 2);
    WBb[e] = __float2half_rn(Whh_b[(size_t)k * 1024 + col]);
  } else if ((e -= 262144) < 8192) {      // flag zero [dir2][slice16][step256]
    FLG[e] = 0u;
  } else if ((e -= 8192) < 524288) {      // depfill -> XT cols [512,544)
    int row = e >> 5, kk = e & 31;
    XT[(size_t)row * 544 + 512 + kk] =
        __float2half_rn(dep_tab[dep_ids[row] * 32 + kk]);
  } else if ((e -= 524288) < 65536) {     // BTuf: N=256, K=256
    int n = e & 255, k = e >> 8;
    BTuf[(size_t)n * 256 + k] = __float2half_rn(Uf[(size_t)k * 256 + n]);
  } else {                                // BTuiou: N=768, K=256
    e -= 65536;
    int n = e % 768, k = e / 768;
    BTuiou[(size_t)n * 256 + k] = __float2half_rn(Uiou[(size_t)k * 768 + n]);
  }
}

// ---------------- MFMA f16 GEMM (dual-job via split_bx) ----------------
// out_mode: 0 = f32 row-major, 1 = f16 row-major, 2 = f16 LSTM staging layout
// [t][slice8][gate4][b64][u32] (M must be 16384 rows = b*256+t, N=1024).
// Blocks with blockIdx.x >= split_bx run the secondary job (BT2/bias2/out2/N2).
__global__ __launch_bounds__(256) void k_mgemm(
    const __half* __restrict__ A16, const __half* __restrict__ BT,
    const float* __restrict__ bias, void* __restrict__ out,
    int N, int K, int lda, int a_embed, int act_tanh, int out_mode,
    EmbArgs ea,
    const __half* __restrict__ BT2, const float* __restrict__ bias2,
    void* __restrict__ out2, int N2, int split_bx) {
  __shared__ _Float16 As[128 * 40];
  __shared__ _Float16 Bs[128 * 40];
  int tid = threadIdx.x;
  int lane = tid & 63, wave = tid >> 6;
  int wm = wave & 1, wn = wave >> 1;
  int bxx = blockIdx.x;
  const __half* BTp = BT; const float* biasp = bias;
  void* outp = out; int Np = N;
  if (bxx >= split_bx) {
    bxx -= split_bx; BTp = BT2; biasp = bias2; outp = out2; Np = N2;
  }
  int col0 = bxx * 128, row0 = blockIdx.y * 128;

  f32x4 acc[4][4];
#pragma unroll
  for (int i = 0; i < 4; ++i)
#pragma unroll
    for (int j = 0; j < 4; ++j) acc[i][j] = (f32x4)0.0f;

  for (int kt = 0; kt < K; kt += 32) {
    __syncthreads();
#pragma unroll
    for (int it = 0; it < 2; ++it) {
      int lin = tid + it * 256;
      int r = lin & 127, kh8 = (lin >> 7) * 8;
      f16x8 va;
      if (!a_embed) {
        va = *(const f16x8*)(A16 + (size_t)(row0 + r) * lda + kt + kh8);
      } else {
        int row = row0 + r;
        int k0 = kt + kh8;
        if (k0 >= 912) {
          va = (f16x8)(_Float16)0.0f;
        } else {
          const float* src;
          if (k0 < 768) {
            src = ea.tf + (size_t)row * 768 + k0;
          } else {
            int b_ = row >> 8, t_ = row & 255;
            if (k0 < 800) src = ea.pos_tab + ea.pos_ids[row] * 32 + (k0 - 768);
            else if (k0 < 832) src = ea.dep_tab + ea.dep_ids[row] * 32 + (k0 - 800);
            else if (k0 < 864) {
              int d = t_ - ea.e1[b_] + 10; d = d < 0 ? 0 : (d > 20 ? 20 : d);
              src = ea.dist_tab + d * 32 + (k0 - 832);
            } else if (k0 < 896) {
              int d = t_ - ea.e2[b_] + 10; d = d < 0 ? 0 : (d > 20 ? 20 : d);
              src = ea.dist_tab + d * 32 + (k0 - 864);
            } else {
              src = ea.sdp_tab + ea.sdp[row] * 16 + (k0 - 896);
            }
          }
          float4 a = *(const float4*)src;
          float4 b2 = *(const float4*)(src + 4);
          va[0] = (_Float16)a.x;  va[1] = (_Float16)a.y;
          va[2] = (_Float16)a.z;  va[3] = (_Float16)a.w;
          va[4] = (_Float16)b2.x; va[5] = (_Float16)b2.y;
          va[6] = (_Float16)b2.z; va[7] = (_Float16)b2.w;
        }
      }
      *(f16x8*)&As[r * 40 + kh8] = va;
      f16x8 vb = *(const f16x8*)(BTp + (size_t)(col0 + r) * K + kt + kh8);
      *(f16x8*)&Bs[r * 40 + kh8] = vb;
    }
    __syncthreads();
    f16x8 af[4], bf[4];
    int kq = (lane >> 4) * 8;
#pragma unroll
    for (int mt = 0; mt < 4; ++mt)
      af[mt] = *(const f16x8*)&As[(wm * 64 + mt * 16 + (lane & 15)) * 40 + kq];
#pragma unroll
    for (int nt = 0; nt < 4; ++nt)
      bf[nt] = *(const f16x8*)&Bs[(wn * 64 + nt * 16 + (lane & 15)) * 40 + kq];
#pragma unroll
    for (int mt = 0; mt < 4; ++mt)
#pragma unroll
      for (int nt = 0; nt < 4; ++nt)
        acc[mt][nt] = __builtin_amdgcn_mfma_f32_16x16x32_f16(
            af[mt], bf[nt], acc[mt][nt], 0, 0, 0);
  }

#pragma unroll
  for (int mt = 0; mt < 4; ++mt) {
#pragma unroll
    for (int nt = 0; nt < 4; ++nt) {
      int col = col0 + wn * 64 + nt * 16 + (lane & 15);
      float bv = biasp[col];
#pragma unroll
      for (int r = 0; r < 4; ++r) {
        int row = row0 + wm * 64 + mt * 16 + (lane >> 4) * 4 + r;
        float v = acc[mt][nt][r] + bv;
        if (act_tanh) v = tanh_fast(v);
        if (out_mode == 0) {
          ((float*)outp)[(size_t)row * Np + col] = v;
        } else if (out_mode == 1) {
          ((__half*)outp)[(size_t)row * Np + col] = __float2half_rn(v);
        } else {
          // LSTM staging: [t][slice8][gate4][b][32 units]
          int b_ = row >> 8, t_ = row & 255;
          int g_ = col >> 8, u_ = col & 255;
          int sl = u_ >> 5, ul = u_ & 31;
          ((__half*)outp)[((((size_t)(t_ * 8 + sl) * 4 + g_) * 64 + b_) * 32) + ul] =
              __float2half_rn(v);
        }
      }
    }
  }
}

// ---------------- BiLSTM v15: 32 thin blocks + hidden-latency micro-opts --
// 16 units/slice, r2 protocol. Poll busy-spins (load RT paces the loop, no
// s_sleep); xW gates for step s+1 prefetched during the rendezvous.
__global__ __launch_bounds__(256, 1) void k_lstm4(
    const __half* __restrict__ XFs, const __half* __restrict__ XBs,
    const __half* __restrict__ WBf, const __half* __restrict__ WBb,
    __half* __restrict__ HexS, unsigned int* __restrict__ flags,
    __half* __restrict__ XT) {
  int bx = blockIdx.x;          // 0..31
  int dir = bx >> 4, slice = bx & 15;
  int tid = threadIdx.x;
  int lane = tid & 63, wave = tid >> 6;
  const __half* xWs = dir ? XBs : XFs;
  const __half* WB = dir ? WBb : WBf;
  __half* hexd = HexS + (size_t)dir * 256 * 16384;  // [step][slice16][b64][u16]
  unsigned int* flg = flags + dir * 4096;           // [slice16][step256]

  __shared__ _Float16 H[64 * 266];   // [b][u], row stride 266 f16
  __shared__ float GT[64 * 69];      // [b][c64], row stride 69 dw (c=ul*4+g)

  // ---- preload B-fragments: 64 cols x 256 k (32 VGPRs)
  // WB pack is [slice8][c128][k256]; slice16 j -> (j>>1, half j&1):
  // c128 = (j&1)*64 + c64, c64 = wave*16 + (lane&15).
  f16x8 bfrag[8];
  {
    int c = (slice & 1) * 64 + wave * 16 + (lane & 15);
#pragma unroll
    for (int kt = 0; kt < 8; ++kt)
      bfrag[kt] = *(const f16x8*)(
          WB + ((size_t)((slice >> 1) * 128 + c) * 256) + kt * 32 +
          (lane >> 4) * 8);
  }
  // ---- zero H
  for (int i = tid; i < 64 * 266 / 8; i += 256)
    ((f16x8*)H)[i] = (f16x8)(_Float16)0.0f;
  float cst[4];
#pragma unroll
  for (int p = 0; p < 4; ++p) cst[p] = 0.0f;
  int b_own = tid >> 2;
  int uc = tid & 3;   // 4-unit chunk within the 16-unit slice
  // xW base offset for this thread (constant across steps)
  size_t xw_off = b_own * 32 + (slice & 1) * 16 + uc * 4;
  // ---- preload xW gates for step 0
  f16x4 xwg[4];
  {
    int t0 = dir ? 255 : 0;
    const __half* xwp = xWs + ((size_t)(t0 * 8 + (slice >> 1)) * 8192) + xw_off;
#pragma unroll
    for (int g = 0; g < 4; ++g) xwg[g] = *(const f16x4*)(xwp + g * 2048);
  }
  __syncthreads();

  for (int s = 0; s < 256; ++s) {
    int t = dir ? (255 - s) : s;

    // ---- MFMA: gates[64 b, 64 c] = H[64,256] @ Wslice[256,64]
    f32x4 acc[4];
#pragma unroll
    for (int mt = 0; mt < 4; ++mt) acc[mt] = (f32x4)0.0f;
#pragma unroll
    for (int kt = 0; kt < 8; ++kt) {
      f16x8 a[4];
#pragma unroll
      for (int mt = 0; mt < 4; ++mt)
        a[mt] = *(const f16x8*)&H[(mt * 16 + (lane & 15)) * 266 + kt * 32 +
                                  (lane >> 4) * 8];
#pragma unroll
      for (int mt = 0; mt < 4; ++mt)
        acc[mt] = __builtin_amdgcn_mfma_f32_16x16x32_f16(
            a[mt], bfrag[kt], acc[mt], 0, 0, 0);
    }
    __syncthreads();  // H consumed; GT fully read (prev update)
    // ---- transpose C-layout -> GT[b][c64]
    {
      int col = wave * 16 + (lane & 15);
#pragma unroll
      for (int mt = 0; mt < 4; ++mt)
#pragma unroll
        for (int r = 0; r < 4; ++r) {
          int b = mt * 16 + (lane >> 4) * 4 + r;
          GT[b * 69 + col] = acc[mt][r];
        }
    }
    __syncthreads();
    // ---- c/h update for own (b_own, units uc*4..uc*4+3)
    PK4 hv;
#pragma unroll
    for (int p = 0; p < 4; ++p) {
      int ul = uc * 4 + p;
      float4 g4 = *(const float4*)&GT[b_own * 69 + 4 * ul];
      float gi = g4.x + (float)xwg[0][p];
      float gf = g4.y + (float)xwg[1][p];
      float gg = g4.z + (float)xwg[2][p];
      float go = g4.w + (float)xwg[3][p];
      cst[p] = sigm(gf) * cst[p] + sigm(gi) * tanh_fast(gg);
      float hn = sigm(go) * tanh_fast(cst[p]);
      hv.h[p] = (_Float16)hn;
    }
    // own h -> LDS H (units slice*16 + uc*4)
    *(f16x4*)&H[b_own * 266 + slice * 16 + uc * 4] = hv.v;

    if (s < 255) {
      __half* hexq = hexd + (size_t)s * 16384;
      // ---- publish directly from registers (block-contiguous 2KB)
      unsigned long long* dst =
          (unsigned long long*)(hexq + slice * 1024 + tid * 4);
      __hip_atomic_store(dst, hv.u64, __ATOMIC_RELAXED,
                         __HIP_MEMORY_SCOPE_AGENT);
      // drain own wave's publish stores to the LLC, then block rendezvous
      asm volatile("s_waitcnt vmcnt(0)" ::: "memory");
      __syncthreads();
      if (tid == 0)
        __hip_atomic_store(&flg[(slice << 8) + s], 1u, __ATOMIC_RELAXED,
                           __HIP_MEMORY_SCOPE_AGENT);
      // XT store AFTER flag (out of the drain path)
      *(f16x4*)(XT + (size_t)((b_own << 8) + t) * 544 + dir * 256 +
                slice * 16 + uc * 4) = hv.v;
      // ---- prefetch next step's xW gates (latency hides under poll+gather)
      f16x4 xwn[4];
      {
        int tn = dir ? (254 - s) : (s + 1);
        const __half* xwp =
            xWs + ((size_t)(tn * 8 + (slice >> 1)) * 8192) + xw_off;
#pragma unroll
        for (int g = 0; g < 4; ++g) xwn[g] = *(const f16x4*)(xwp + g * 2048);
      }
      // poll the 15 peer flags in parallel (lanes 0..15); load RT paces loop
      if (tid < 16 && tid != slice) {
        while (__hip_atomic_load(&flg[(tid << 8) + s], __ATOMIC_RELAXED,
                                 __HIP_MEMORY_SCOPE_AGENT) == 0u) {}
      }
      __syncthreads();
      // ---- gather 15 peer slices, contiguous loads (step-unique, MLP)
#pragma unroll
      for (int i = 0; i < 15; ++i) {
        int ps = i + (i >= slice ? 1 : 0);
        f16x4 pv = *(const f16x4*)(hexq + ps * 1024 + tid * 4);
        *(f16x4*)&H[b_own * 266 + ps * 16 + uc * 4] = pv;
      }
      __syncthreads();  // H complete before next step's MFMA
#pragma unroll
      for (int g = 0; g < 4; ++g) xwg[g] = xwn[g];
    } else {
      *(f16x4*)(XT + (size_t)((b_own << 8) + t) * 544 + dir * 256 +
                slice * 16 + uc * 4) = hv.v;
    }
  }
}

// ---------------- MFMA f16 dual-job tree GEMM (stages 0-2 only) ----------
// job0 (blocks [0,nb0)): FCb — band rows (a_mode1), epi2, N=256, bias none
// job1 (blocks [nb0,..)): IOUL — sibling-pair-sum rows (a_mode2), N=768
// A = H (f32, converted f16 in staging); B = f16 packs; acc f32; K=256.
__global__ __launch_bounds__(256) void k_tgemm(
    const float* __restrict__ A,
    const __half* __restrict__ BT0, float* __restrict__ Cv0, int M0,
    int band_lo0, int blog0,
    const __half* __restrict__ BT1, float* __restrict__ Cv1, int M1,
    int band_lo1, int blog1, int nb0,
    const int* __restrict__ dep_heads,
    const float* __restrict__ xWf, const float* __restrict__ c_buf) {
  __shared__ _Float16 As[128 * 40];
  __shared__ _Float16 Bs[128 * 40];
  int tid = threadIdx.x;
  int lane = tid & 63, wave = tid >> 6;
  int wm = wave & 1, wn = wave >> 1;
  int f = blockIdx.x;
  const __half* BT; float* Cv; int M, N, band_lo, blog, amode, epi;
  int bx, by;
  if (f < nb0) {
    BT = BT0; Cv = Cv0; M = M0; N = 256; band_lo = band_lo0; blog = blog0;
    amode = 1; epi = 2; bx = f & 1; by = f >> 1;
  } else {
    f -= nb0;
    BT = BT1; Cv = Cv1; M = M1; N = 768; band_lo = band_lo1; blog = blog1;
    amode = 2; epi = 0; bx = f % 6; by = f / 6;
  }
  int col0 = bx * 128, row0 = by * 128;
  int bmask = (1 << blog) - 1;

  f32x4 acc[4][4];
#pragma unroll
  for (int i = 0; i < 4; ++i)
#pragma unroll
    for (int j = 0; j < 4; ++j) acc[i][j] = (f32x4)0.0f;

  for (int kt = 0; kt < 256; kt += 32) {
    __syncthreads();
#pragma unroll
    for (int it = 0; it < 2; ++it) {
      int lin = tid + it * 256;
      int r = lin & 127, kh8 = (lin >> 7) * 8;
      int row = row0 + r;
      f16x8 va = (f16x8)(_Float16)0.0f;
      if (row < M) {
        if (amode == 1) {
          int b_ = row >> blog, t_ = band_lo + (row & bmask);
          const float* src = A + (size_t)((b_ << 8) + t_) * 256 + kt + kh8;
          float4 a4 = *(const float4*)src;
          float4 b4 = *(const float4*)(src + 4);
          va[0] = (_Float16)a4.x; va[1] = (_Float16)a4.y;
          va[2] = (_Float16)a4.z; va[3] = (_Float16)a4.w;
          va[4] = (_Float16)b4.x; va[5] = (_Float16)b4.y;
          va[6] = (_Float16)b4.z; va[7] = (_Float16)b4.w;
        } else {
          int b_ = row >> blog, p_ = band_lo + (row & bmask);
          const float* p0 = A + (size_t)((b_ << 8) + 2 * p_) * 256 + kt + kh8;
          float4 x0a = {0.0f, 0.0f, 0.0f, 0.0f};
          float4 x0b = {0.0f, 0.0f, 0.0f, 0.0f};
          if (2 * p_ != 0) {
            x0a = *(const float4*)p0;
            x0b = *(const float4*)(p0 + 4);
          }
          float4 x1a = *(const float4*)(p0 + 256);
          float4 x1b = *(const float4*)(p0 + 260);
          va[0] = (_Float16)(x0a.x + x1a.x); va[1] = (_Float16)(x0a.y + x1a.y);
          va[2] = (_Float16)(x0a.z + x1a.z); va[3] = (_Float16)(x0a.w + x1a.w);
          va[4] = (_Float16)(x0b.x + x1b.x); va[5] = (_Float16)(x0b.y + x1b.y);
          va[6] = (_Float16)(x0b.z + x1b.z); va[7] = (_Float16)(x0b.w + x1b.w);
        }
      }
      *(f16x8*)&As[r * 40 + kh8] = va;
      f16x8 vb = *(const f16x8*)(BT + (size_t)(col0 + r) * 256 + kt + kh8);
      *(f16x8*)&Bs[r * 40 + kh8] = vb;
    }
    __syncthreads();
    f16x8 af[4], bf[4];
    int kq = (lane >> 4) * 8;
#pragma unroll
    for (int mt = 0; mt < 4; ++mt)
      af[mt] = *(const f16x8*)&As[(wm * 64 + mt * 16 + (lane & 15)) * 40 + kq];
#pragma unroll
    for (int nt = 0; nt < 4; ++nt)
      bf[nt] = *(const f16x8*)&Bs[(wn * 64 + nt * 16 + (lane & 15)) * 40 + kq];
#pragma unroll
    for (int mt = 0; mt < 4; ++mt)
#pragma unroll
      for (int nt = 0; nt < 4; ++nt)
        acc[mt][nt] = __builtin_amdgcn_mfma_f32_16x16x32_f16(
            af[mt], bf[nt], acc[mt][nt], 0, 0, 0);
  }

#pragma unroll
  for (int mt = 0; mt < 4; ++mt) {
#pragma unroll
    for (int nt = 0; nt < 4; ++nt) {
      int col = col0 + wn * 64 + nt * 16 + (lane & 15);
#pragma unroll
      for (int r = 0; r < 4; ++r) {
        int row = row0 + wm * 64 + mt * 16 + (lane >> 4) * 4 + r;
        if (row >= M) continue;
        float v = acc[mt][nt][r];
        if (epi == 2) {
          int b_ = row >> blog, t_ = band_lo + (row & bmask);
          int par = dep_heads[(b_ << 8) + t_];
          float m = (par != t_) ? 1.0f : 0.0f;
          float xwv = xWf[(size_t)((b_ << 8) + par) * 256 + col];
          float cv = c_buf[(size_t)((b_ << 8) + t_) * 256 + col];
          v = sigm(v + xwv) * cv * m;
        }
        Cv[(size_t)row * N + col] = v;
      }
    }
  }
}

// ---------------- tree tail: stages plo 8,4,2,1,0 in ONE kernel ----------
// 64 blocks = 1/batch (batch-local, no cross-block deps). H/C rows <32 in
// LDS (rows 0..15 zero-init so the masked t=0 child cannot inject garbage).
// Per level: f-gate dots (Uf col j coalesced), iou dots (3 cols/thread),
// then the k_tgemm-epi2 / k_update formulas verbatim in fp32.
__global__ __launch_bounds__(256) void k_tree_tail(
    const float* __restrict__ xWiou, const float* __restrict__ xWf,
    const int* __restrict__ dep_heads,
    const float* __restrict__ Uf, const float* __restrict__ Uiou,
    float* __restrict__ h_buf, float* __restrict__ c_buf) {
  int b = blockIdx.x, j = threadIdx.x;
  __shared__ float Hs[32 * 256];
  __shared__ float Cs[32 * 256];
  for (int t = 0; t < 16; ++t) {
    Hs[t * 256 + j] = 0.0f;
    Cs[t * 256 + j] = 0.0f;
  }
  for (int t = 16; t < 32; ++t) {
    size_t row = (size_t)((b << 8) + t);
    Hs[t * 256 + j] = h_buf[row * 256 + j];
    Cs[t * 256 + j] = c_buf[row * 256 + j];
  }
  __syncthreads();
  const int plos5[5] = {8, 4, 2, 1, 0};
  const int nps5[5]  = {8, 4, 2, 1, 1};
  for (int lv = 0; lv < 5; ++lv) {
    int plo = plos5[lv], np = nps5[lv];
    int nch = 2 * np;
    int c0 = 2 * plo;  // first child row
    // ---- f-gate dots: fd[ci] = sum_k Hs[c0+ci][k] * Uf[k][j]
    float fd[16];
#pragma unroll
    for (int ci = 0; ci < 16; ++ci) fd[ci] = 0.0f;
    for (int k = 0; k < 256; ++k) {
      float u = Uf[(size_t)k * 256 + j];
      for (int ci = 0; ci < nch; ++ci)
        fd[ci] += Hs[(c0 + ci) * 256 + k] * u;
    }
    // ---- iou dots: io{0,1,2}[p] = sum_k hsum[p][k] * Uiou[k][{j,j+256,j+512}]
    float io0[8], io1[8], io2[8];
#pragma unroll
    for (int p = 0; p < 8; ++p) { io0[p] = 0.0f; io1[p] = 0.0f; io2[p] = 0.0f; }
    for (int k = 0; k < 256; ++k) {
      float u0 = Uiou[(size_t)k * 768 + j];
      float u1 = Uiou[(size_t)k * 768 + 256 + j];
      float u2 = Uiou[(size_t)k * 768 + 512 + j];
      for (int p = 0; p < np; ++p) {
        int pp = plo + p;
        float hs = Hs[(2 * pp + 1) * 256 + k] +
                   ((2 * pp) ? Hs[2 * pp * 256 + k] : 0.0f);
        io0[p] += hs * u0; io1[p] += hs * u1; io2[p] += hs * u2;
      }
    }
    __syncthreads();  // all dot reads complete before parent-row writes
    for (int p = 0; p < np; ++p) {
      int pp = plo + p;
      size_t prow = (size_t)((b << 8) + pp);
      int ta = 2 * pp, tb = 2 * pp + 1;
      int para = dep_heads[(b << 8) + ta];
      int parb = dep_heads[(b << 8) + tb];
      float ma = (para != ta) ? 1.0f : 0.0f;
      float mb = (parb != tb) ? 1.0f : 0.0f;
      float fca = sigm(fd[ta - c0] + xWf[(size_t)((b << 8) + para) * 256 + j]) *
                  Cs[ta * 256 + j] * ma;
      float fcb = sigm(fd[tb - c0] + xWf[(size_t)((b << 8) + parb) * 256 + j]) *
                  Cs[tb * 256 + j] * mb;
      float fcsum = fca + fcb;
      float iv = xWiou[prow * 768 + j] + io0[p];
      float ov = xWiou[prow * 768 + 256 + j] + io1[p];
      float uv = xWiou[prow * 768 + 512 + j] + io2[p];
      float cc = sigm(iv) * tanh_fast(uv) + fcsum;
      float hh = sigm(ov) * tanh_fast(cc);
      Cs[pp * 256 + j] = cc;
      Hs[pp * 256 + j] = hh;
    }
    __syncthreads();
  }
  // write back h rows 0..15 (classifier may read any root index)
  for (int t = 0; t < 16; ++t)
    h_buf[(size_t)((b << 8) + t) * 256 + j] = Hs[t * 256 + j];
}

// ---------------- tree leaves: t in [128,256) ----------------
__global__ __launch_bounds__(256) void k_leaves(
    const float* __restrict__ xWiou, float* __restrict__ h_buf,
    float* __restrict__ c_buf) {
  int r = blockIdx.x;  // 0..8191
  int b = r >> 7, t = 128 + (r & 127);
  size_t row = (size_t)((b << 8) + t);
  int j = threadIdx.x;
  float i = xWiou[row * 768 + j];
  float o = xWiou[row * 768 + 256 + j];
  float u = xWiou[row * 768 + 512 + j];
  float c = sigm(i) * tanh_fast(u);
  float h = sigm(o) * tanh_fast(c);
  c_buf[row * 256 + j] = c;
  h_buf[row * 256 + j] = h;
}

// ---------------- tree stage update (stages 0-2 only) ----------------
__global__ __launch_bounds__(256) void k_update(
    const float* __restrict__ xWiou, const float* __restrict__ iou_lin,
    const float* __restrict__ FC, float* __restrict__ h_buf,
    float* __restrict__ c_buf, int plo, int nplog2) {
  int r = blockIdx.x, j = threadIdx.x;
  int npm = (1 << nplog2) - 1;
  int b = r >> nplog2, loc = r & npm, p = plo + loc;
  size_t row = (size_t)((b << 8) + p);
  float i = xWiou[row * 768 + j] + iou_lin[(size_t)r * 768 + j];
  float o = xWiou[row * 768 + 256 + j] + iou_lin[(size_t)r * 768 + 256 + j];
  float u = xWiou[row * 768 + 512 + j] + iou_lin[(size_t)r * 768 + 512 + j];
  int nch = 2 << nplog2;
  float fc = FC[(size_t)(b * nch + 2 * loc) * 256 + j] +
             FC[(size_t)(b * nch + 2 * loc + 1) * 256 + j];
  float c = sigm(i) * tanh_fast(u) + fc;
  float h = sigm(o) * tanh_fast(c);
  c_buf[row * 256 + j] = c;
  h_buf[row * 256 + j] = h;
}

// ---------------- classifier ----------------
__global__ __launch_bounds__(256) void k_classifier(
    const float* __restrict__ h_buf, const int* __restrict__ root_idx,
    const float* __restrict__ W1, const float* __restrict__ b1,
    const float* __restrict__ W2, const float* __restrict__ b2,
    float* __restrict__ out) {
  int b = blockIdx.x, j = threadIdx.x;
  __shared__ float hroot[256];
  __shared__ float hid[256];
  int root = root_idx[b];
  hroot[j] = h_buf[(size_t)((b << 8) + root) * 256 + j];
  __syncthreads();
  float acc = b1[j];
  for (int k = 0; k < 256; ++k) acc += hroot[k] * W1[k * 256 + j];
  hid[j] = fmaxf(acc, 0.0f);
  __syncthreads();
  if (j < 10) {
    float o = b2[j];
    for (int k = 0; k < 256; ++k) o += hid[k] * W2[k * 10 + j];
    out[b * 10 + j] = o;
  }
}

// ---------------------------------------------------------------------------
extern "C" void kernel_launch(void* const* d_in, const int* in_sizes, int n_in,
                              void* d_out, int out_size, void* d_ws,
                              size_t ws_size, hipStream_t stream) {
  (void)in_sizes; (void)n_in; (void)out_size; (void)ws_size;
  const float* tf       = (const float*)d_in[0];
  const int*   pos_ids  = (const int*)d_in[1];
  const int*   dep_ids  = (const int*)d_in[2];
  const int*   e1       = (const int*)d_in[3];
  const int*   e2       = (const int*)d_in[4];
  const int*   sdp      = (const int*)d_in[5];
  const int*   heads    = (const int*)d_in[6];
  const int*   root     = (const int*)d_in[7];
  const float* pos_tab  = (const float*)d_in[8];
  const float* dep_tab  = (const float*)d_in[9];
  const float* dist_tab = (const float*)d_in[10];
  const float* sdp_tab  = (const float*)d_in[11];
  const float* W_ft     = (const float*)d_in[12];
  const float* b_ft     = (const float*)d_in[13];
  const float* Wih_f    = (const float*)d_in[14];
  const float* Whh_f    = (const float*)d_in[15];
  const float* bl_f     = (const float*)d_in[16];
  const float* Wih_b    = (const float*)d_in[17];
  const float* Whh_b    = (const float*)d_in[18];
  const float* bl_b     = (const float*)d_in[19];
  const float* W_iou    = (const float*)d_in[20];
  const float* U_iou    = (const float*)d_in[21];
  const float* b_iou    = (const float*)d_in[22];
  const float* Wf_t     = (const float*)d_in[23];
  const float* Uf_t     = (const float*)d_in[24];
  const float* bf_t     = (const float*)d_in[25];
  const float* W1       = (const float*)d_in[26];
  const float* b1       = (const float*)d_in[27];
  const float* W2       = (const float*)d_in[28];
  const float* b2       = (const float*)d_in[29];

  // ---- workspace (lifetime-overlaid; peak 122.16 MB < proven-safe 122.7 MB)
  char* ws = (char*)d_ws;
  __half* XF    = (__half*)(ws + 0ull);            // 33.5MB  phase2->3 (staged layout)
  __half* XB    = (__half*)(ws + 33554432ull);     // 33.5MB  phase2->3 (staged layout)
  float*  XWIOU = (float*)(ws + 0ull);             // 50.3MB  phase5->6
  float*  XWF   = (float*)(ws + 50331648ull);      // 16.8MB  phase5->6
  __half* XT    = (__half*)(ws + 67108864ull);     // 17.8MB  phase3->5
  float*  FCb   = (float*)(ws + 67108864ull);      //  8.4MB  phase6
  float*  IOUL  = (float*)(ws + 75497472ull);      // 12.6MB  phase6
  float*  H     = (float*)(ws + 88080384ull);      // 16.8MB  phase6
  __half* T     = (__half*)(ws + 88080384ull);     // 16.8MB  phase1->2 (over H)
  __half* HexS  = (__half*)(ws + 88080384ull);     // 16.8MB  phase3 (over T/H)
  float*  C     = (float*)(ws + 104857600ull);     // 16.8MB  phase6 -> 121634816
  // packs live inside C region (dead before C written):
  __half* BTft  = (__half*)(ws + 104857600ull);    // 950,272
  __half* BTwhf = (__half*)(ws + 105807872ull);    // 1,048,576
  __half* BTwhb = (__half*)(ws + 106856448ull);    // 1,048,576
  __half* BTiou = (__half*)(ws + 107905024ull);    // 835,584
  __half* BTf   = (__half*)(ws + 108740608ull);    // 278,528
  __half* WBf   = (__half*)(ws + 109019136ull);    // 524,288
  __half* WBb   = (__half*)(ws + 109543424ull);    // 524,288
  unsigned int* FLG = (unsigned int*)(ws + 110198784ull);  // 32,768 (16 slices)
  // tree packs (live through phase 6) placed AFTER C:
  __half* BTuiou = (__half*)(ws + 121634816ull);   // 393,216
  __half* BTuf   = (__half*)(ws + 122028032ull);   // 131,072 -> 122159104

  EmbArgs ea{tf, pos_ids, dep_ids, e1, e2, sdp, pos_tab, dep_tab, dist_tab, sdp_tab};

  // 0. merged prep: packs + zft + WB packs + flag zero + depfill + tree packs
  k_prep<<<dim3(13280), dim3(256), 0, stream>>>(
      W_ft, BTft, Wih_f, BTwhf, Wih_b, BTwhb, W_iou, BTiou, Wf_t, BTf,
      Whh_f, WBf, Whh_b, WBb, FLG, dep_ids, dep_tab, XT,
      Uf_t, BTuf, U_iou, BTuiou);

  // 1. T = tanh(embed @ W_ft + b_ft)  [f16 out, embed fused]
  k_mgemm<<<dim3(4, 128), dim3(256), 0, stream>>>(
      nullptr, BTft, b_ft, (void*)T, 512, 928, 0, 1, 1, 1, ea,
      BTft, b_ft, (void*)T, 512, 10000);
  // 2. xW_f / xW_b merged (one launch): bx<8 -> XF job, bx>=8 -> XB job
  k_mgemm<<<dim3(16, 128), dim3(256), 0, stream>>>(
      T, BTwhf, bl_f, (void*)XF, 1024, 512, 512, 0, 0, 2, ea,
      BTwhb, bl_b, (void*)XB, 1024, 8);
  // 3. BiLSTM -> XT cols [0,512)   (HexS overlays dead T; 32 thin blocks)
  k_lstm4<<<dim3(32), dim3(256), 0, stream>>>(XF, XB, WBf, WBb, HexS, FLG, XT);
  // 5. xWiou / xWf merged (one launch): bx<6 -> XWIOU, bx>=6 -> XWF
  k_mgemm<<<dim3(8, 128), dim3(256), 0, stream>>>(
      XT, BTiou, b_iou, (void*)XWIOU, 768, 544, 544, 0, 0, 0, ea,
      BTf, bf_t, (void*)XWF, 256, 6);
  // 6. tree: leaves, 3 big MFMA stages, then the 5-stage tail in one kernel
  k_leaves<<<dim3(8192), dim3(256), 0, stream>>>(XWIOU, H, C);
  const int plos[3] = {64, 32, 16};
  const int lgs[3]  = {6, 5, 4};
  for (int s = 0; s < 3; ++s) {
    int plo = plos[s], lg = lgs[s];
    int npar = 1 << lg;
    int Mch = 128 * npar;
    int Mp = 64 * npar;
    int nb0 = 2 * npar;                     // FCb: 2 col-blocks x npar rows
    int nb1 = 6 * ((Mp + 127) / 128);       // IOUL: 6 col-blocks x ceil rows
    k_tgemm<<<dim3(nb0 + nb1), dim3(256), 0, stream>>>(
        H, BTuf, FCb, Mch, 2 * plo, lg + 1,
        BTuiou, IOUL, Mp, plo, lg, nb0, heads, XWF, C);
    k_update<<<dim3(Mp), dim3(256), 0, stream>>>(XWIOU, IOUL, FCb, H, C, plo, lg);
  }
  k_tree_tail<<<dim3(64), dim3(256), 0, stream>>>(XWIOU, XWF, heads,
                                                  Uf_t, U_iou, H, C);
  // 7. classifier
  k_classifier<<<dim3(64), dim3(256), 0, stream>>>(H, root, W1, b1, W2, b2,
                                                   (float*)d_out);
}

// Round 16
// 1550.655 us; speedup vs baseline: 1.7437x; 1.7437x over previous
//
#include <hip/hip_runtime.h>
#include <hip/hip_fp16.h>
#include <math.h>

// ---------------------------------------------------------------------------
// RelationExtractionModel B=64,T=256. Round 25: fix r24's k_tree_tail —
// the runtime-bounded accumulator arrays (fd[nch], io[np]) were allocated
// in SCRATCH (rule: runtime-indexed arrays -> local memory), making the
// tail 1283us at 8% VALU. Levels are now template<PLO,NP> instantiations
// with compile-time bounds: accumulators in registers, loops unrolled.
// Math byte-identical to r24 (which PASSED numerically). Everything else
// = round 23 structure (1624us verified).
// ---------------------------------------------------------------------------

typedef _Float16 f16x8 __attribute__((ext_vector_type(8)));
typedef _Float16 f16x4 __attribute__((ext_vector_type(4)));
typedef float    f32x4 __attribute__((ext_vector_type(4)));

union PK { _Float16 h[8]; unsigned long long u64[2]; f16x8 v; };
union PK4 { _Float16 h[4]; unsigned long long u64; f16x4 v; };

#define LOG2E 1.44269504088896340736f

__device__ __forceinline__ float fexp2(float x) {
  return __builtin_amdgcn_exp2f(x);
}
__device__ __forceinline__ float frcp(float x) {
  return __builtin_amdgcn_rcpf(x);
}
__device__ __forceinline__ float sigm(float x) {
  return frcp(1.0f + fexp2(-LOG2E * x));
}
__device__ __forceinline__ float tanh_fast(float x) {
  return 1.0f - 2.0f * frcp(1.0f + fexp2(2.0f * LOG2E * x));
}

struct EmbArgs {
  const float* tf; const int* pos_ids; const int* dep_ids;
  const int* e1; const int* e2; const int* sdp;
  const float* pos_tab; const float* dep_tab; const float* dist_tab;
  const float* sdp_tab;
};

// ---------------- merged prep: packs + zft + WB packs + flag zero + depfill
// ranges (all multiples of 256; formulas verbatim from proven kernels):
//  BTft 466944 | zft 8192 | BTwhf 524288 | BTwhb 524288 | BTiou 417792 |
//  BTf 139264 | WBf 262144 | WBb 262144 | FLG 8192 | depfill 524288 |
//  BTuf 65536 | BTuiou 196608   -> total 3399680 = 13280 blocks x 256
__global__ __launch_bounds__(256) void k_prep(
    const float* __restrict__ W_ft, __half* __restrict__ BTft,
    const float* __restrict__ Wih_f, __half* __restrict__ BTwhf,
    const float* __restrict__ Wih_b, __half* __restrict__ BTwhb,
    const float* __restrict__ W_iou, __half* __restrict__ BTiou,
    const float* __restrict__ Wf_t, __half* __restrict__ BTf,
    const float* __restrict__ Whh_f, __half* __restrict__ WBf,
    const float* __restrict__ Whh_b, __half* __restrict__ WBb,
    unsigned int* __restrict__ FLG,
    const int* __restrict__ dep_ids, const float* __restrict__ dep_tab,
    __half* __restrict__ XT,
    const float* __restrict__ Uf, __half* __restrict__ BTuf,
    const float* __restrict__ Uiou, __half* __restrict__ BTuiou) {
  int e = blockIdx.x * 256 + threadIdx.x;
  if (e < 466944) {                       // BTft: n fastest (coalesced read)
    int n = e & 511, k = e >> 9;          // k<912
    BTft[(size_t)n * 928 + k] = __float2half_rn(W_ft[(size_t)k * 512 + n]);
  } else if ((e -= 466944) < 8192) {      // zft pad cols [912,928)
    int n = e >> 4, kk = e & 15;
    BTft[(size_t)n * 928 + 912 + kk] = __float2half_rn(0.0f);
  } else if ((e -= 8192) < 524288) {      // BTwhf
    int n = e & 1023, k = e >> 10;        // k<512
    BTwhf[(size_t)n * 512 + k] = __float2half_rn(Wih_f[(size_t)k * 1024 + n]);
  } else if ((e -= 524288) < 524288) {    // BTwhb
    int n = e & 1023, k = e >> 10;
    BTwhb[(size_t)n * 512 + k] = __float2half_rn(Wih_b[(size_t)k * 1024 + n]);
  } else if ((e -= 524288) < 417792) {    // BTiou: N=768, K=544
    int n = e % 768, k = e / 768;
    BTiou[(size_t)n * 544 + k] = __float2half_rn(W_iou[(size_t)k * 768 + n]);
  } else if ((e -= 417792) < 139264) {    // BTf: N=256, K=544
    int n = e & 255, k = e >> 8;
    BTf[(size_t)n * 544 + k] = __float2half_rn(Wf_t[(size_t)k * 256 + n]);
  } else if ((e -= 139264) < 262144) {    // WBf  [r11 k_packWB verbatim]
    int k = e & 255, c = (e >> 8) & 127, j = e >> 15;
    int col = (c & 3) * 256 + j * 32 + (c >> 2);
    WBf[e] = __float2half_rn(Whh_f[(size_t)k * 1024 + col]);
  } else if ((e -= 262144) < 262144) {    // WBb
    int k = e & 255, c = (e >> 8) & 127, j = e >> 15;
    int col = (c & 3) * 256 + j * 32 + (c >> 2);
    WBb[e] = __float2half_rn(Whh_b[(size_t)k * 1024 + col]);
  } else if ((e -= 262144) < 8192) {      // flag zero [dir2][slice16][step256]
    FLG[e] = 0u;
  } else if ((e -= 8192) < 524288) {      // depfill -> XT cols [512,544)
    int row = e >> 5, kk = e & 31;
    XT[(size_t)row * 544 + 512 + kk] =
        __float2half_rn(dep_tab[dep_ids[row] * 32 + kk]);
  } else if ((e -= 524288) < 65536) {     // BTuf: N=256, K=256
    int n = e & 255, k = e >> 8;
    BTuf[(size_t)n * 256 + k] = __float2half_rn(Uf[(size_t)k * 256 + n]);
  } else {                                // BTuiou: N=768, K=256
    e -= 65536;
    int n = e % 768, k = e / 768;
    BTuiou[(size_t)n * 256 + k] = __float2half_rn(Uiou[(size_t)k * 768 + n]);
  }
}

// ---------------- MFMA f16 GEMM (dual-job via split_bx) ----------------
// out_mode: 0 = f32 row-major, 1 = f16 row-major, 2 = f16 LSTM staging layout
// [t][slice8][gate4][b64][u32] (M must be 16384 rows = b*256+t, N=1024).
// Blocks with blockIdx.x >= split_bx run the secondary job (BT2/bias2/out2/N2).
__global__ __launch_bounds__(256) void k_mgemm(
    const __half* __restrict__ A16, const __half* __restrict__ BT,
    const float* __restrict__ bias, void* __restrict__ out,
    int N, int K, int lda, int a_embed, int act_tanh, int out_mode,
    EmbArgs ea,
    const __half* __restrict__ BT2, const float* __restrict__ bias2,
    void* __restrict__ out2, int N2, int split_bx) {
  __shared__ _Float16 As[128 * 40];
  __shared__ _Float16 Bs[128 * 40];
  int tid = threadIdx.x;
  int lane = tid & 63, wave = tid >> 6;
  int wm = wave & 1, wn = wave >> 1;
  int bxx = blockIdx.x;
  const __half* BTp = BT; const float* biasp = bias;
  void* outp = out; int Np = N;
  if (bxx >= split_bx) {
    bxx -= split_bx; BTp = BT2; biasp = bias2; outp = out2; Np = N2;
  }
  int col0 = bxx * 128, row0 = blockIdx.y * 128;

  f32x4 acc[4][4];
#pragma unroll
  for (int i = 0; i < 4; ++i)
#pragma unroll
    for (int j = 0; j < 4; ++j) acc[i][j] = (f32x4)0.0f;

  for (int kt = 0; kt < K; kt += 32) {
    __syncthreads();
#pragma unroll
    for (int it = 0; it < 2; ++it) {
      int lin = tid + it * 256;
      int r = lin & 127, kh8 = (lin >> 7) * 8;
      f16x8 va;
      if (!a_embed) {
        va = *(const f16x8*)(A16 + (size_t)(row0 + r) * lda + kt + kh8);
      } else {
        int row = row0 + r;
        int k0 = kt + kh8;
        if (k0 >= 912) {
          va = (f16x8)(_Float16)0.0f;
        } else {
          const float* src;
          if (k0 < 768) {
            src = ea.tf + (size_t)row * 768 + k0;
          } else {
            int b_ = row >> 8, t_ = row & 255;
            if (k0 < 800) src = ea.pos_tab + ea.pos_ids[row] * 32 + (k0 - 768);
            else if (k0 < 832) src = ea.dep_tab + ea.dep_ids[row] * 32 + (k0 - 800);
            else if (k0 < 864) {
              int d = t_ - ea.e1[b_] + 10; d = d < 0 ? 0 : (d > 20 ? 20 : d);
              src = ea.dist_tab + d * 32 + (k0 - 832);
            } else if (k0 < 896) {
              int d = t_ - ea.e2[b_] + 10; d = d < 0 ? 0 : (d > 20 ? 20 : d);
              src = ea.dist_tab + d * 32 + (k0 - 864);
            } else {
              src = ea.sdp_tab + ea.sdp[row] * 16 + (k0 - 896);
            }
          }
          float4 a = *(const float4*)src;
          float4 b2 = *(const float4*)(src + 4);
          va[0] = (_Float16)a.x;  va[1] = (_Float16)a.y;
          va[2] = (_Float16)a.z;  va[3] = (_Float16)a.w;
          va[4] = (_Float16)b2.x; va[5] = (_Float16)b2.y;
          va[6] = (_Float16)b2.z; va[7] = (_Float16)b2.w;
        }
      }
      *(f16x8*)&As[r * 40 + kh8] = va;
      f16x8 vb = *(const f16x8*)(BTp + (size_t)(col0 + r) * K + kt + kh8);
      *(f16x8*)&Bs[r * 40 + kh8] = vb;
    }
    __syncthreads();
    f16x8 af[4], bf[4];
    int kq = (lane >> 4) * 8;
#pragma unroll
    for (int mt = 0; mt < 4; ++mt)
      af[mt] = *(const f16x8*)&As[(wm * 64 + mt * 16 + (lane & 15)) * 40 + kq];
#pragma unroll
    for (int nt = 0; nt < 4; ++nt)
      bf[nt] = *(const f16x8*)&Bs[(wn * 64 + nt * 16 + (lane & 15)) * 40 + kq];
#pragma unroll
    for (int mt = 0; mt < 4; ++mt)
#pragma unroll
      for (int nt = 0; nt < 4; ++nt)
        acc[mt][nt] = __builtin_amdgcn_mfma_f32_16x16x32_f16(
            af[mt], bf[nt], acc[mt][nt], 0, 0, 0);
  }

#pragma unroll
  for (int mt = 0; mt < 4; ++mt) {
#pragma unroll
    for (int nt = 0; nt < 4; ++nt) {
      int col = col0 + wn * 64 + nt * 16 + (lane & 15);
      float bv = biasp[col];
#pragma unroll
      for (int r = 0; r < 4; ++r) {
        int row = row0 + wm * 64 + mt * 16 + (lane >> 4) * 4 + r;
        float v = acc[mt][nt][r] + bv;
        if (act_tanh) v = tanh_fast(v);
        if (out_mode == 0) {
          ((float*)outp)[(size_t)row * Np + col] = v;
        } else if (out_mode == 1) {
          ((__half*)outp)[(size_t)row * Np + col] = __float2half_rn(v);
        } else {
          // LSTM staging: [t][slice8][gate4][b][32 units]
          int b_ = row >> 8, t_ = row & 255;
          int g_ = col >> 8, u_ = col & 255;
          int sl = u_ >> 5, ul = u_ & 31;
          ((__half*)outp)[((((size_t)(t_ * 8 + sl) * 4 + g_) * 64 + b_) * 32) + ul] =
              __float2half_rn(v);
        }
      }
    }
  }
}

// ---------------- BiLSTM v15: 32 thin blocks + hidden-latency micro-opts --
// 16 units/slice, r2 protocol. Poll busy-spins (load RT paces the loop, no
// s_sleep); xW gates for step s+1 prefetched during the rendezvous.
__global__ __launch_bounds__(256, 1) void k_lstm4(
    const __half* __restrict__ XFs, const __half* __restrict__ XBs,
    const __half* __restrict__ WBf, const __half* __restrict__ WBb,
    __half* __restrict__ HexS, unsigned int* __restrict__ flags,
    __half* __restrict__ XT) {
  int bx = blockIdx.x;          // 0..31
  int dir = bx >> 4, slice = bx & 15;
  int tid = threadIdx.x;
  int lane = tid & 63, wave = tid >> 6;
  const __half* xWs = dir ? XBs : XFs;
  const __half* WB = dir ? WBb : WBf;
  __half* hexd = HexS + (size_t)dir * 256 * 16384;  // [step][slice16][b64][u16]
  unsigned int* flg = flags + dir * 4096;           // [slice16][step256]

  __shared__ _Float16 H[64 * 266];   // [b][u], row stride 266 f16
  __shared__ float GT[64 * 69];      // [b][c64], row stride 69 dw (c=ul*4+g)

  // ---- preload B-fragments: 64 cols x 256 k (32 VGPRs)
  f16x8 bfrag[8];
  {
    int c = (slice & 1) * 64 + wave * 16 + (lane & 15);
#pragma unroll
    for (int kt = 0; kt < 8; ++kt)
      bfrag[kt] = *(const f16x8*)(
          WB + ((size_t)((slice >> 1) * 128 + c) * 256) + kt * 32 +
          (lane >> 4) * 8);
  }
  // ---- zero H
  for (int i = tid; i < 64 * 266 / 8; i += 256)
    ((f16x8*)H)[i] = (f16x8)(_Float16)0.0f;
  float cst[4];
#pragma unroll
  for (int p = 0; p < 4; ++p) cst[p] = 0.0f;
  int b_own = tid >> 2;
  int uc = tid & 3;   // 4-unit chunk within the 16-unit slice
  size_t xw_off = b_own * 32 + (slice & 1) * 16 + uc * 4;
  f16x4 xwg[4];
  {
    int t0 = dir ? 255 : 0;
    const __half* xwp = xWs + ((size_t)(t0 * 8 + (slice >> 1)) * 8192) + xw_off;
#pragma unroll
    for (int g = 0; g < 4; ++g) xwg[g] = *(const f16x4*)(xwp + g * 2048);
  }
  __syncthreads();

  for (int s = 0; s < 256; ++s) {
    int t = dir ? (255 - s) : s;

    // ---- MFMA: gates[64 b, 64 c] = H[64,256] @ Wslice[256,64]
    f32x4 acc[4];
#pragma unroll
    for (int mt = 0; mt < 4; ++mt) acc[mt] = (f32x4)0.0f;
#pragma unroll
    for (int kt = 0; kt < 8; ++kt) {
      f16x8 a[4];
#pragma unroll
      for (int mt = 0; mt < 4; ++mt)
        a[mt] = *(const f16x8*)&H[(mt * 16 + (lane & 15)) * 266 + kt * 32 +
                                  (lane >> 4) * 8];
#pragma unroll
      for (int mt = 0; mt < 4; ++mt)
        acc[mt] = __builtin_amdgcn_mfma_f32_16x16x32_f16(
            a[mt], bfrag[kt], acc[mt], 0, 0, 0);
    }
    __syncthreads();  // H consumed; GT fully read (prev update)
    // ---- transpose C-layout -> GT[b][c64]
    {
      int col = wave * 16 + (lane & 15);
#pragma unroll
      for (int mt = 0; mt < 4; ++mt)
#pragma unroll
        for (int r = 0; r < 4; ++r) {
          int b = mt * 16 + (lane >> 4) * 4 + r;
          GT[b * 69 + col] = acc[mt][r];
        }
    }
    __syncthreads();
    // ---- c/h update for own (b_own, units uc*4..uc*4+3)
    PK4 hv;
#pragma unroll
    for (int p = 0; p < 4; ++p) {
      int ul = uc * 4 + p;
      float4 g4 = *(const float4*)&GT[b_own * 69 + 4 * ul];
      float gi = g4.x + (float)xwg[0][p];
      float gf = g4.y + (float)xwg[1][p];
      float gg = g4.z + (float)xwg[2][p];
      float go = g4.w + (float)xwg[3][p];
      cst[p] = sigm(gf) * cst[p] + sigm(gi) * tanh_fast(gg);
      float hn = sigm(go) * tanh_fast(cst[p]);
      hv.h[p] = (_Float16)hn;
    }
    // own h -> LDS H (units slice*16 + uc*4)
    *(f16x4*)&H[b_own * 266 + slice * 16 + uc * 4] = hv.v;

    if (s < 255) {
      __half* hexq = hexd + (size_t)s * 16384;
      // ---- publish directly from registers (block-contiguous 2KB)
      unsigned long long* dst =
          (unsigned long long*)(hexq + slice * 1024 + tid * 4);
      __hip_atomic_store(dst, hv.u64, __ATOMIC_RELAXED,
                         __HIP_MEMORY_SCOPE_AGENT);
      // drain own wave's publish stores to the LLC, then block rendezvous
      asm volatile("s_waitcnt vmcnt(0)" ::: "memory");
      __syncthreads();
      if (tid == 0)
        __hip_atomic_store(&flg[(slice << 8) + s], 1u, __ATOMIC_RELAXED,
                           __HIP_MEMORY_SCOPE_AGENT);
      // XT store AFTER flag (out of the drain path)
      *(f16x4*)(XT + (size_t)((b_own << 8) + t) * 544 + dir * 256 +
                slice * 16 + uc * 4) = hv.v;
      // ---- prefetch next step's xW gates (latency hides under poll+gather)
      f16x4 xwn[4];
      {
        int tn = dir ? (254 - s) : (s + 1);
        const __half* xwp =
            xWs + ((size_t)(tn * 8 + (slice >> 1)) * 8192) + xw_off;
#pragma unroll
        for (int g = 0; g < 4; ++g) xwn[g] = *(const f16x4*)(xwp + g * 2048);
      }
      // poll the 15 peer flags in parallel (lanes 0..15); load RT paces loop
      if (tid < 16 && tid != slice) {
        while (__hip_atomic_load(&flg[(tid << 8) + s], __ATOMIC_RELAXED,
                                 __HIP_MEMORY_SCOPE_AGENT) == 0u) {}
      }
      __syncthreads();
      // ---- gather 15 peer slices, contiguous loads (step-unique, MLP)
#pragma unroll
      for (int i = 0; i < 15; ++i) {
        int ps = i + (i >= slice ? 1 : 0);
        f16x4 pv = *(const f16x4*)(hexq + ps * 1024 + tid * 4);
        *(f16x4*)&H[b_own * 266 + ps * 16 + uc * 4] = pv;
      }
      __syncthreads();  // H complete before next step's MFMA
#pragma unroll
      for (int g = 0; g < 4; ++g) xwg[g] = xwn[g];
    } else {
      *(f16x4*)(XT + (size_t)((b_own << 8) + t) * 544 + dir * 256 +
                slice * 16 + uc * 4) = hv.v;
    }
  }
}

// ---------------- MFMA f16 dual-job tree GEMM (stages 0-2 only) ----------
__global__ __launch_bounds__(256) void k_tgemm(
    const float* __restrict__ A,
    const __half* __restrict__ BT0, float* __restrict__ Cv0, int M0,
    int band_lo0, int blog0,
    const __half* __restrict__ BT1, float* __restrict__ Cv1, int M1,
    int band_lo1, int blog1, int nb0,
    const int* __restrict__ dep_heads,
    const float* __restrict__ xWf, const float* __restrict__ c_buf) {
  __shared__ _Float16 As[128 * 40];
  __shared__ _Float16 Bs[128 * 40];
  int tid = threadIdx.x;
  int lane = tid & 63, wave = tid >> 6;
  int wm = wave & 1, wn = wave >> 1;
  int f = blockIdx.x;
  const __half* BT; float* Cv; int M, N, band_lo, blog, amode, epi;
  int bx, by;
  if (f < nb0) {
    BT = BT0; Cv = Cv0; M = M0; N = 256; band_lo = band_lo0; blog = blog0;
    amode = 1; epi = 2; bx = f & 1; by = f >> 1;
  } else {
    f -= nb0;
    BT = BT1; Cv = Cv1; M = M1; N = 768; band_lo = band_lo1; blog = blog1;
    amode = 2; epi = 0; bx = f % 6; by = f / 6;
  }
  int col0 = bx * 128, row0 = by * 128;
  int bmask = (1 << blog) - 1;

  f32x4 acc[4][4];
#pragma unroll
  for (int i = 0; i < 4; ++i)
#pragma unroll
    for (int j = 0; j < 4; ++j) acc[i][j] = (f32x4)0.0f;

  for (int kt = 0; kt < 256; kt += 32) {
    __syncthreads();
#pragma unroll
    for (int it = 0; it < 2; ++it) {
      int lin = tid + it * 256;
      int r = lin & 127, kh8 = (lin >> 7) * 8;
      int row = row0 + r;
      f16x8 va = (f16x8)(_Float16)0.0f;
      if (row < M) {
        if (amode == 1) {
          int b_ = row >> blog, t_ = band_lo + (row & bmask);
          const float* src = A + (size_t)((b_ << 8) + t_) * 256 + kt + kh8;
          float4 a4 = *(const float4*)src;
          float4 b4 = *(const float4*)(src + 4);
          va[0] = (_Float16)a4.x; va[1] = (_Float16)a4.y;
          va[2] = (_Float16)a4.z; va[3] = (_Float16)a4.w;
          va[4] = (_Float16)b4.x; va[5] = (_Float16)b4.y;
          va[6] = (_Float16)b4.z; va[7] = (_Float16)b4.w;
        } else {
          int b_ = row >> blog, p_ = band_lo + (row & bmask);
          const float* p0 = A + (size_t)((b_ << 8) + 2 * p_) * 256 + kt + kh8;
          float4 x0a = {0.0f, 0.0f, 0.0f, 0.0f};
          float4 x0b = {0.0f, 0.0f, 0.0f, 0.0f};
          if (2 * p_ != 0) {
            x0a = *(const float4*)p0;
            x0b = *(const float4*)(p0 + 4);
          }
          float4 x1a = *(const float4*)(p0 + 256);
          float4 x1b = *(const float4*)(p0 + 260);
          va[0] = (_Float16)(x0a.x + x1a.x); va[1] = (_Float16)(x0a.y + x1a.y);
          va[2] = (_Float16)(x0a.z + x1a.z); va[3] = (_Float16)(x0a.w + x1a.w);
          va[4] = (_Float16)(x0b.x + x1b.x); va[5] = (_Float16)(x0b.y + x1b.y);
          va[6] = (_Float16)(x0b.z + x1b.z); va[7] = (_Float16)(x0b.w + x1b.w);
        }
      }
      *(f16x8*)&As[r * 40 + kh8] = va;
      f16x8 vb = *(const f16x8*)(BT + (size_t)(col0 + r) * 256 + kt + kh8);
      *(f16x8*)&Bs[r * 40 + kh8] = vb;
    }
    __syncthreads();
    f16x8 af[4], bf[4];
    int kq = (lane >> 4) * 8;
#pragma unroll
    for (int mt = 0; mt < 4; ++mt)
      af[mt] = *(const f16x8*)&As[(wm * 64 + mt * 16 + (lane & 15)) * 40 + kq];
#pragma unroll
    for (int nt = 0; nt < 4; ++nt)
      bf[nt] = *(const f16x8*)&Bs[(wn * 64 + nt * 16 + (lane & 15)) * 40 + kq];
#pragma unroll
    for (int mt = 0; mt < 4; ++mt)
#pragma unroll
      for (int nt = 0; nt < 4; ++nt)
        acc[mt][nt] = __builtin_amdgcn_mfma_f32_16x16x32_f16(
            af[mt], bf[nt], acc[mt][nt], 0, 0, 0);
  }

#pragma unroll
  for (int mt = 0; mt < 4; ++mt) {
#pragma unroll
    for (int nt = 0; nt < 4; ++nt) {
      int col = col0 + wn * 64 + nt * 16 + (lane & 15);
#pragma unroll
      for (int r = 0; r < 4; ++r) {
        int row = row0 + wm * 64 + mt * 16 + (lane >> 4) * 4 + r;
        if (row >= M) continue;
        float v = acc[mt][nt][r];
        if (epi == 2) {
          int b_ = row >> blog, t_ = band_lo + (row & bmask);
          int par = dep_heads[(b_ << 8) + t_];
          float m = (par != t_) ? 1.0f : 0.0f;
          float xwv = xWf[(size_t)((b_ << 8) + par) * 256 + col];
          float cv = c_buf[(size_t)((b_ << 8) + t_) * 256 + col];
          v = sigm(v + xwv) * cv * m;
        }
        Cv[(size_t)row * N + col] = v;
      }
    }
  }
}

// ---------------- tree tail level: compile-time bounds (registers!) ------
template <int PLO, int NP>
__device__ __forceinline__ void tree_level(
    int b, int j, float* __restrict__ Hs, float* __restrict__ Cs,
    const float* __restrict__ xWiou, const float* __restrict__ xWf,
    const int* __restrict__ dep_heads,
    const float* __restrict__ Uf, const float* __restrict__ Uiou) {
  constexpr int NCH = 2 * NP;
  constexpr int C0 = 2 * PLO;
  float fd[NCH];
#pragma unroll
  for (int ci = 0; ci < NCH; ++ci) fd[ci] = 0.0f;
  for (int k = 0; k < 256; ++k) {
    float u = Uf[(size_t)k * 256 + j];
#pragma unroll
    for (int ci = 0; ci < NCH; ++ci)
      fd[ci] += Hs[(C0 + ci) * 256 + k] * u;
  }
  float io0[NP], io1[NP], io2[NP];
#pragma unroll
  for (int p = 0; p < NP; ++p) { io0[p] = 0.0f; io1[p] = 0.0f; io2[p] = 0.0f; }
  for (int k = 0; k < 256; ++k) {
    float u0 = Uiou[(size_t)k * 768 + j];
    float u1 = Uiou[(size_t)k * 768 + 256 + j];
    float u2 = Uiou[(size_t)k * 768 + 512 + j];
#pragma unroll
    for (int p = 0; p < NP; ++p) {
      constexpr bool has0 = (PLO != 0);
      int pp = PLO + p;
      float hs = Hs[(2 * pp + 1) * 256 + k];
      if (has0 || p > 0) hs += Hs[2 * pp * 256 + k];
      io0[p] += hs * u0; io1[p] += hs * u1; io2[p] += hs * u2;
    }
  }
  __syncthreads();  // all dot reads complete before parent-row writes
#pragma unroll
  for (int p = 0; p < NP; ++p) {
    int pp = PLO + p;
    size_t prow = (size_t)((b << 8) + pp);
    int ta = 2 * pp, tb = 2 * pp + 1;
    int para = dep_heads[(b << 8) + ta];
    int parb = dep_heads[(b << 8) + tb];
    float ma = (para != ta) ? 1.0f : 0.0f;
    float mb = (parb != tb) ? 1.0f : 0.0f;
    float fca = sigm(fd[2 * p] + xWf[(size_t)((b << 8) + para) * 256 + j]) *
                Cs[ta * 256 + j] * ma;
    float fcb = sigm(fd[2 * p + 1] + xWf[(size_t)((b << 8) + parb) * 256 + j]) *
                Cs[tb * 256 + j] * mb;
    float fcsum = fca + fcb;
    float iv = xWiou[prow * 768 + j] + io0[p];
    float ov = xWiou[prow * 768 + 256 + j] + io1[p];
    float uv = xWiou[prow * 768 + 512 + j] + io2[p];
    float cc = sigm(iv) * tanh_fast(uv) + fcsum;
    float hh = sigm(ov) * tanh_fast(cc);
    Cs[pp * 256 + j] = cc;
    Hs[pp * 256 + j] = hh;
  }
  __syncthreads();
}

// ---------------- tree tail: stages plo 8,4,2,1,0 in ONE kernel ----------
// 64 blocks = 1/batch. H/C rows <32 in LDS (rows 0..15 zero-init). All
// level bounds compile-time -> accumulators in registers (r24 fix).
__global__ __launch_bounds__(256) void k_tree_tail(
    const float* __restrict__ xWiou, const float* __restrict__ xWf,
    const int* __restrict__ dep_heads,
    const float* __restrict__ Uf, const float* __restrict__ Uiou,
    float* __restrict__ h_buf, float* __restrict__ c_buf) {
  int b = blockIdx.x, j = threadIdx.x;
  __shared__ float Hs[32 * 256];
  __shared__ float Cs[32 * 256];
  for (int t = 0; t < 16; ++t) {
    Hs[t * 256 + j] = 0.0f;
    Cs[t * 256 + j] = 0.0f;
  }
  for (int t = 16; t < 32; ++t) {
    size_t row = (size_t)((b << 8) + t);
    Hs[t * 256 + j] = h_buf[row * 256 + j];
    Cs[t * 256 + j] = c_buf[row * 256 + j];
  }
  __syncthreads();
  tree_level<8, 8>(b, j, Hs, Cs, xWiou, xWf, dep_heads, Uf, Uiou);
  tree_level<4, 4>(b, j, Hs, Cs, xWiou, xWf, dep_heads, Uf, Uiou);
  tree_level<2, 2>(b, j, Hs, Cs, xWiou, xWf, dep_heads, Uf, Uiou);
  tree_level<1, 1>(b, j, Hs, Cs, xWiou, xWf, dep_heads, Uf, Uiou);
  tree_level<0, 1>(b, j, Hs, Cs, xWiou, xWf, dep_heads, Uf, Uiou);
  // write back h rows 0..15 (classifier may read any root index)
  for (int t = 0; t < 16; ++t)
    h_buf[(size_t)((b << 8) + t) * 256 + j] = Hs[t * 256 + j];
}

// ---------------- tree leaves: t in [128,256) ----------------
__global__ __launch_bounds__(256) void k_leaves(
    const float* __restrict__ xWiou, float* __restrict__ h_buf,
    float* __restrict__ c_buf) {
  int r = blockIdx.x;  // 0..8191
  int b = r >> 7, t = 128 + (r & 127);
  size_t row = (size_t)((b << 8) + t);
  int j = threadIdx.x;
  float i = xWiou[row * 768 + j];
  float o = xWiou[row * 768 + 256 + j];
  float u = xWiou[row * 768 + 512 + j];
  float c = sigm(i) * tanh_fast(u);
  float h = sigm(o) * tanh_fast(c);
  c_buf[row * 256 + j] = c;
  h_buf[row * 256 + j] = h;
}

// ---------------- tree stage update (stages 0-2 only) ----------------
__global__ __launch_bounds__(256) void k_update(
    const float* __restrict__ xWiou, const float* __restrict__ iou_lin,
    const float* __restrict__ FC, float* __restrict__ h_buf,
    float* __restrict__ c_buf, int plo, int nplog2) {
  int r = blockIdx.x, j = threadIdx.x;
  int npm = (1 << nplog2) - 1;
  int b = r >> nplog2, loc = r & npm, p = plo + loc;
  size_t row = (size_t)((b << 8) + p);
  float i = xWiou[row * 768 + j] + iou_lin[(size_t)r * 768 + j];
  float o = xWiou[row * 768 + 256 + j] + iou_lin[(size_t)r * 768 + 256 + j];
  float u = xWiou[row * 768 + 512 + j] + iou_lin[(size_t)r * 768 + 512 + j];
  int nch = 2 << nplog2;
  float fc = FC[(size_t)(b * nch + 2 * loc) * 256 + j] +
             FC[(size_t)(b * nch + 2 * loc + 1) * 256 + j];
  float c = sigm(i) * tanh_fast(u) + fc;
  float h = sigm(o) * tanh_fast(c);
  c_buf[row * 256 + j] = c;
  h_buf[row * 256 + j] = h;
}

// ---------------- classifier ----------------
__global__ __launch_bounds__(256) void k_classifier(
    const float* __restrict__ h_buf, const int* __restrict__ root_idx,
    const float* __restrict__ W1, const float* __restrict__ b1,
    const float* __restrict__ W2, const float* __restrict__ b2,
    float* __restrict__ out) {
  int b = blockIdx.x, j = threadIdx.x;
  __shared__ float hroot[256];
  __shared__ float hid[256];
  int root = root_idx[b];
  hroot[j] = h_buf[(size_t)((b << 8) + root) * 256 + j];
  __syncthreads();
  float acc = b1[j];
  for (int k = 0; k < 256; ++k) acc += hroot[k] * W1[k * 256 + j];
  hid[j] = fmaxf(acc, 0.0f);
  __syncthreads();
  if (j < 10) {
    float o = b2[j];
    for (int k = 0; k < 256; ++k) o += hid[k] * W2[k * 10 + j];
    out[b * 10 + j] = o;
  }
}

// ---------------------------------------------------------------------------
extern "C" void kernel_launch(void* const* d_in, const int* in_sizes, int n_in,
                              void* d_out, int out_size, void* d_ws,
                              size_t ws_size, hipStream_t stream) {
  (void)in_sizes; (void)n_in; (void)out_size; (void)ws_size;
  const float* tf       = (const float*)d_in[0];
  const int*   pos_ids  = (const int*)d_in[1];
  const int*   dep_ids  = (const int*)d_in[2];
  const int*   e1       = (const int*)d_in[3];
  const int*   e2       = (const int*)d_in[4];
  const int*   sdp      = (const int*)d_in[5];
  const int*   heads    = (const int*)d_in[6];
  const int*   root     = (const int*)d_in[7];
  const float* pos_tab  = (const float*)d_in[8];
  const float* dep_tab  = (const float*)d_in[9];
  const float* dist_tab = (const float*)d_in[10];
  const float* sdp_tab  = (const float*)d_in[11];
  const float* W_ft     = (const float*)d_in[12];
  const float* b_ft     = (const float*)d_in[13];
  const float* Wih_f    = (const float*)d_in[14];
  const float* Whh_f    = (const float*)d_in[15];
  const float* bl_f     = (const float*)d_in[16];
  const float* Wih_b    = (const float*)d_in[17];
  const float* Whh_b    = (const float*)d_in[18];
  const float* bl_b     = (const float*)d_in[19];
  const float* W_iou    = (const float*)d_in[20];
  const float* U_iou    = (const float*)d_in[21];
  const float* b_iou    = (const float*)d_in[22];
  const float* Wf_t     = (const float*)d_in[23];
  const float* Uf_t     = (const float*)d_in[24];
  const float* bf_t     = (const float*)d_in[25];
  const float* W1       = (const float*)d_in[26];
  const float* b1       = (const float*)d_in[27];
  const float* W2       = (const float*)d_in[28];
  const float* b2       = (const float*)d_in[29];

  // ---- workspace (lifetime-overlaid; peak 122.16 MB < proven-safe 122.7 MB)
  char* ws = (char*)d_ws;
  __half* XF    = (__half*)(ws + 0ull);            // 33.5MB  phase2->3 (staged layout)
  __half* XB    = (__half*)(ws + 33554432ull);     // 33.5MB  phase2->3 (staged layout)
  float*  XWIOU = (float*)(ws + 0ull);             // 50.3MB  phase5->6
  float*  XWF   = (float*)(ws + 50331648ull);      // 16.8MB  phase5->6
  __half* XT    = (__half*)(ws + 67108864ull);     // 17.8MB  phase3->5
  float*  FCb   = (float*)(ws + 67108864ull);      //  8.4MB  phase6
  float*  IOUL  = (float*)(ws + 75497472ull);      // 12.6MB  phase6
  float*  H     = (float*)(ws + 88080384ull);      // 16.8MB  phase6
  __half* T     = (__half*)(ws + 88080384ull);     // 16.8MB  phase1->2 (over H)
  __half* HexS  = (__half*)(ws + 88080384ull);     // 16.8MB  phase3 (over T/H)
  float*  C     = (float*)(ws + 104857600ull);     // 16.8MB  phase6 -> 121634816
  // packs live inside C region (dead before C written):
  __half* BTft  = (__half*)(ws + 104857600ull);    // 950,272
  __half* BTwhf = (__half*)(ws + 105807872ull);    // 1,048,576
  __half* BTwhb = (__half*)(ws + 106856448ull);    // 1,048,576
  __half* BTiou = (__half*)(ws + 107905024ull);    // 835,584
  __half* BTf   = (__half*)(ws + 108740608ull);    // 278,528
  __half* WBf   = (__half*)(ws + 109019136ull);    // 524,288
  __half* WBb   = (__half*)(ws + 109543424ull);    // 524,288
  unsigned int* FLG = (unsigned int*)(ws + 110198784ull);  // 32,768 (16 slices)
  // tree packs (live through phase 6) placed AFTER C:
  __half* BTuiou = (__half*)(ws + 121634816ull);   // 393,216
  __half* BTuf   = (__half*)(ws + 122028032ull);   // 131,072 -> 122159104

  EmbArgs ea{tf, pos_ids, dep_ids, e1, e2, sdp, pos_tab, dep_tab, dist_tab, sdp_tab};

  // 0. merged prep: packs + zft + WB packs + flag zero + depfill + tree packs
  k_prep<<<dim3(13280), dim3(256), 0, stream>>>(
      W_ft, BTft, Wih_f, BTwhf, Wih_b, BTwhb, W_iou, BTiou, Wf_t, BTf,
      Whh_f, WBf, Whh_b, WBb, FLG, dep_ids, dep_tab, XT,
      Uf_t, BTuf, U_iou, BTuiou);

  // 1. T = tanh(embed @ W_ft + b_ft)  [f16 out, embed fused]
  k_mgemm<<<dim3(4, 128), dim3(256), 0, stream>>>(
      nullptr, BTft, b_ft, (void*)T, 512, 928, 0, 1, 1, 1, ea,
      BTft, b_ft, (void*)T, 512, 10000);
  // 2. xW_f / xW_b merged (one launch): bx<8 -> XF job, bx>=8 -> XB job
  k_mgemm<<<dim3(16, 128), dim3(256), 0, stream>>>(
      T, BTwhf, bl_f, (void*)XF, 1024, 512, 512, 0, 0, 2, ea,
      BTwhb, bl_b, (void*)XB, 1024, 8);
  // 3. BiLSTM -> XT cols [0,512)   (HexS overlays dead T; 32 thin blocks)
  k_lstm4<<<dim3(32), dim3(256), 0, stream>>>(XF, XB, WBf, WBb, HexS, FLG, XT);
  // 5. xWiou / xWf merged (one launch): bx<6 -> XWIOU, bx>=6 -> XWF
  k_mgemm<<<dim3(8, 128), dim3(256), 0, stream>>>(
      XT, BTiou, b_iou, (void*)XWIOU, 768, 544, 544, 0, 0, 0, ea,
      BTf, bf_t, (void*)XWF, 256, 6);
  // 6. tree: leaves, 3 big MFMA stages, then the 5-stage tail in one kernel
  k_leaves<<<dim3(8192), dim3(256), 0, stream>>>(XWIOU, H, C);
  const int plos[3] = {64, 32, 16};
  const int lgs[3]  = {6, 5, 4};
  for (int s = 0; s < 3; ++s) {
    int plo = plos[s], lg = lgs[s];
    int npar = 1 << lg;
    int Mch = 128 * npar;
    int Mp = 64 * npar;
    int nb0 = 2 * npar;                     // FCb: 2 col-blocks x npar rows
    int nb1 = 6 * ((Mp + 127) / 128);       // IOUL: 6 col-blocks x ceil rows
    k_tgemm<<<dim3(nb0 + nb1), dim3(256), 0, stream>>>(
        H, BTuf, FCb, Mch, 2 * plo, lg + 1,
        BTuiou, IOUL, Mp, plo, lg, nb0, heads, XWF, C);
    k_update<<<dim3(Mp), dim3(256), 0, stream>>>(XWIOU, IOUL, FCb, H, C, plo, lg);
  }
  k_tree_tail<<<dim3(64), dim3(256), 0, stream>>>(XWIOU, XWF, heads,
                                                  Uf_t, U_iou, H, C);
  // 7. classifier
  k_classifier<<<dim3(64), dim3(256), 0, stream>>>(H, root, W1, b1, W2, b2,
                                                   (float*)d_out);
}

// Round 17
// 1310.308 us; speedup vs baseline: 2.0636x; 1.1834x over previous
//
#include <hip/hip_runtime.h>
#include <hip/hip_fp16.h>
#include <math.h>

// ---------------------------------------------------------------------------
// RelationExtractionModel B=64,T=256. Round 26: batch-halved thin-slice
// BiLSTM — 64 blocks = 2 dirs x 16 slices x 2 batch-halves(32). Halves the
// per-block serial compute again (16 MFMA/wave, 2 gate-units/thread) while
// the r2 rendezvous protocol stays byte-identical per (dir,half) group of
// 16 blocks (groups independent; same flag/poll/batched-gather). Same
// transformation class as r22 (which delivered -0.71us/step). Everything
// else = round 25 (1551us verified: tree_tail registers fix, busy-poll,
// xW prefetch, merged launches, f16 MFMA tree).
// ---------------------------------------------------------------------------

typedef _Float16 f16x8 __attribute__((ext_vector_type(8)));
typedef _Float16 f16x4 __attribute__((ext_vector_type(4)));
typedef _Float16 f16x2 __attribute__((ext_vector_type(2)));
typedef float    f32x4 __attribute__((ext_vector_type(4)));

union PK { _Float16 h[8]; unsigned long long u64[2]; f16x8 v; };
union PK2 { _Float16 h[2]; unsigned int u32; f16x2 v; };

#define LOG2E 1.44269504088896340736f

__device__ __forceinline__ float fexp2(float x) {
  return __builtin_amdgcn_exp2f(x);
}
__device__ __forceinline__ float frcp(float x) {
  return __builtin_amdgcn_rcpf(x);
}
__device__ __forceinline__ float sigm(float x) {
  return frcp(1.0f + fexp2(-LOG2E * x));
}
__device__ __forceinline__ float tanh_fast(float x) {
  return 1.0f - 2.0f * frcp(1.0f + fexp2(2.0f * LOG2E * x));
}

struct EmbArgs {
  const float* tf; const int* pos_ids; const int* dep_ids;
  const int* e1; const int* e2; const int* sdp;
  const float* pos_tab; const float* dep_tab; const float* dist_tab;
  const float* sdp_tab;
};

// ---------------- merged prep: packs + zft + WB packs + flag zero + depfill
// ranges (all multiples of 256; formulas verbatim from proven kernels):
//  BTft 466944 | zft 8192 | BTwhf 524288 | BTwhb 524288 | BTiou 417792 |
//  BTf 139264 | WBf 262144 | WBb 262144 | FLG 16384 | depfill 524288 |
//  BTuf 65536 | BTuiou 196608   -> total 3407872 = 13312 blocks x 256
__global__ __launch_bounds__(256) void k_prep(
    const float* __restrict__ W_ft, __half* __restrict__ BTft,
    const float* __restrict__ Wih_f, __half* __restrict__ BTwhf,
    const float* __restrict__ Wih_b, __half* __restrict__ BTwhb,
    const float* __restrict__ W_iou, __half* __restrict__ BTiou,
    const float* __restrict__ Wf_t, __half* __restrict__ BTf,
    const float* __restrict__ Whh_f, __half* __restrict__ WBf,
    const float* __restrict__ Whh_b, __half* __restrict__ WBb,
    unsigned int* __restrict__ FLG,
    const int* __restrict__ dep_ids, const float* __restrict__ dep_tab,
    __half* __restrict__ XT,
    const float* __restrict__ Uf, __half* __restrict__ BTuf,
    const float* __restrict__ Uiou, __half* __restrict__ BTuiou) {
  int e = blockIdx.x * 256 + threadIdx.x;
  if (e < 466944) {                       // BTft: n fastest (coalesced read)
    int n = e & 511, k = e >> 9;          // k<912
    BTft[(size_t)n * 928 + k] = __float2half_rn(W_ft[(size_t)k * 512 + n]);
  } else if ((e -= 466944) < 8192) {      // zft pad cols [912,928)
    int n = e >> 4, kk = e & 15;
    BTft[(size_t)n * 928 + 912 + kk] = __float2half_rn(0.0f);
  } else if ((e -= 8192) < 524288) {      // BTwhf
    int n = e & 1023, k = e >> 10;        // k<512
    BTwhf[(size_t)n * 512 + k] = __float2half_rn(Wih_f[(size_t)k * 1024 + n]);
  } else if ((e -= 524288) < 524288) {    // BTwhb
    int n = e & 1023, k = e >> 10;
    BTwhb[(size_t)n * 512 + k] = __float2half_rn(Wih_b[(size_t)k * 1024 + n]);
  } else if ((e -= 524288) < 417792) {    // BTiou: N=768, K=544
    int n = e % 768, k = e / 768;
    BTiou[(size_t)n * 544 + k] = __float2half_rn(W_iou[(size_t)k * 768 + n]);
  } else if ((e -= 417792) < 139264) {    // BTf: N=256, K=544
    int n = e & 255, k = e >> 8;
    BTf[(size_t)n * 544 + k] = __float2half_rn(Wf_t[(size_t)k * 256 + n]);
  } else if ((e -= 139264) < 262144) {    // WBf  [r11 k_packWB verbatim]
    int k = e & 255, c = (e >> 8) & 127, j = e >> 15;
    int col = (c & 3) * 256 + j * 32 + (c >> 2);
    WBf[e] = __float2half_rn(Whh_f[(size_t)k * 1024 + col]);
  } else if ((e -= 262144) < 262144) {    // WBb
    int k = e & 255, c = (e >> 8) & 127, j = e >> 15;
    int col = (c & 3) * 256 + j * 32 + (c >> 2);
    WBb[e] = __float2half_rn(Whh_b[(size_t)k * 1024 + col]);
  } else if ((e -= 262144) < 16384) {     // flag zero [dir2][bh2][slice16][256]
    FLG[e] = 0u;
  } else if ((e -= 16384) < 524288) {     // depfill -> XT cols [512,544)
    int row = e >> 5, kk = e & 31;
    XT[(size_t)row * 544 + 512 + kk] =
        __float2half_rn(dep_tab[dep_ids[row] * 32 + kk]);
  } else if ((e -= 524288) < 65536) {     // BTuf: N=256, K=256
    int n = e & 255, k = e >> 8;
    BTuf[(size_t)n * 256 + k] = __float2half_rn(Uf[(size_t)k * 256 + n]);
  } else {                                // BTuiou: N=768, K=256
    e -= 65536;
    int n = e % 768, k = e / 768;
    BTuiou[(size_t)n * 256 + k] = __float2half_rn(Uiou[(size_t)k * 768 + n]);
  }
}

// ---------------- MFMA f16 GEMM (dual-job via split_bx) ----------------
// out_mode: 0 = f32 row-major, 1 = f16 row-major, 2 = f16 LSTM staging layout
// [t][slice8][gate4][b64][u32] (M must be 16384 rows = b*256+t, N=1024).
// Blocks with blockIdx.x >= split_bx run the secondary job (BT2/bias2/out2/N2).
__global__ __launch_bounds__(256) void k_mgemm(
    const __half* __restrict__ A16, const __half* __restrict__ BT,
    const float* __restrict__ bias, void* __restrict__ out,
    int N, int K, int lda, int a_embed, int act_tanh, int out_mode,
    EmbArgs ea,
    const __half* __restrict__ BT2, const float* __restrict__ bias2,
    void* __restrict__ out2, int N2, int split_bx) {
  __shared__ _Float16 As[128 * 40];
  __shared__ _Float16 Bs[128 * 40];
  int tid = threadIdx.x;
  int lane = tid & 63, wave = tid >> 6;
  int wm = wave & 1, wn = wave >> 1;
  int bxx = blockIdx.x;
  const __half* BTp = BT; const float* biasp = bias;
  void* outp = out; int Np = N;
  if (bxx >= split_bx) {
    bxx -= split_bx; BTp = BT2; biasp = bias2; outp = out2; Np = N2;
  }
  int col0 = bxx * 128, row0 = blockIdx.y * 128;

  f32x4 acc[4][4];
#pragma unroll
  for (int i = 0; i < 4; ++i)
#pragma unroll
    for (int j = 0; j < 4; ++j) acc[i][j] = (f32x4)0.0f;

  for (int kt = 0; kt < K; kt += 32) {
    __syncthreads();
#pragma unroll
    for (int it = 0; it < 2; ++it) {
      int lin = tid + it * 256;
      int r = lin & 127, kh8 = (lin >> 7) * 8;
      f16x8 va;
      if (!a_embed) {
        va = *(const f16x8*)(A16 + (size_t)(row0 + r) * lda + kt + kh8);
      } else {
        int row = row0 + r;
        int k0 = kt + kh8;
        if (k0 >= 912) {
          va = (f16x8)(_Float16)0.0f;
        } else {
          const float* src;
          if (k0 < 768) {
            src = ea.tf + (size_t)row * 768 + k0;
          } else {
            int b_ = row >> 8, t_ = row & 255;
            if (k0 < 800) src = ea.pos_tab + ea.pos_ids[row] * 32 + (k0 - 768);
            else if (k0 < 832) src = ea.dep_tab + ea.dep_ids[row] * 32 + (k0 - 800);
            else if (k0 < 864) {
              int d = t_ - ea.e1[b_] + 10; d = d < 0 ? 0 : (d > 20 ? 20 : d);
              src = ea.dist_tab + d * 32 + (k0 - 832);
            } else if (k0 < 896) {
              int d = t_ - ea.e2[b_] + 10; d = d < 0 ? 0 : (d > 20 ? 20 : d);
              src = ea.dist_tab + d * 32 + (k0 - 864);
            } else {
              src = ea.sdp_tab + ea.sdp[row] * 16 + (k0 - 896);
            }
          }
          float4 a = *(const float4*)src;
          float4 b2 = *(const float4*)(src + 4);
          va[0] = (_Float16)a.x;  va[1] = (_Float16)a.y;
          va[2] = (_Float16)a.z;  va[3] = (_Float16)a.w;
          va[4] = (_Float16)b2.x; va[5] = (_Float16)b2.y;
          va[6] = (_Float16)b2.z; va[7] = (_Float16)b2.w;
        }
      }
      *(f16x8*)&As[r * 40 + kh8] = va;
      f16x8 vb = *(const f16x8*)(BTp + (size_t)(col0 + r) * K + kt + kh8);
      *(f16x8*)&Bs[r * 40 + kh8] = vb;
    }
    __syncthreads();
    f16x8 af[4], bf[4];
    int kq = (lane >> 4) * 8;
#pragma unroll
    for (int mt = 0; mt < 4; ++mt)
      af[mt] = *(const f16x8*)&As[(wm * 64 + mt * 16 + (lane & 15)) * 40 + kq];
#pragma unroll
    for (int nt = 0; nt < 4; ++nt)
      bf[nt] = *(const f16x8*)&Bs[(wn * 64 + nt * 16 + (lane & 15)) * 40 + kq];
#pragma unroll
    for (int mt = 0; mt < 4; ++mt)
#pragma unroll
      for (int nt = 0; nt < 4; ++nt)
        acc[mt][nt] = __builtin_amdgcn_mfma_f32_16x16x32_f16(
            af[mt], bf[nt], acc[mt][nt], 0, 0, 0);
  }

#pragma unroll
  for (int mt = 0; mt < 4; ++mt) {
#pragma unroll
    for (int nt = 0; nt < 4; ++nt) {
      int col = col0 + wn * 64 + nt * 16 + (lane & 15);
      float bv = biasp[col];
#pragma unroll
      for (int r = 0; r < 4; ++r) {
        int row = row0 + wm * 64 + mt * 16 + (lane >> 4) * 4 + r;
        float v = acc[mt][nt][r] + bv;
        if (act_tanh) v = tanh_fast(v);
        if (out_mode == 0) {
          ((float*)outp)[(size_t)row * Np + col] = v;
        } else if (out_mode == 1) {
          ((__half*)outp)[(size_t)row * Np + col] = __float2half_rn(v);
        } else {
          // LSTM staging: [t][slice8][gate4][b][32 units]
          int b_ = row >> 8, t_ = row & 255;
          int g_ = col >> 8, u_ = col & 255;
          int sl = u_ >> 5, ul = u_ & 31;
          ((__half*)outp)[((((size_t)(t_ * 8 + sl) * 4 + g_) * 64 + b_) * 32) + ul] =
              __float2half_rn(v);
        }
      }
    }
  }
}

// ---------------- BiLSTM v16: 64 blocks = 2 dir x 16 slice x 2 batch-half -
// 16 units/slice, 32 batches/block. r2 protocol per (dir,half) group of 16
// blocks (independent groups). 16 MFMA/wave, 2 gate-units/thread. Busy-poll,
// xW prefetch under the rendezvous (r23/25 proven micro-opts).
__global__ __launch_bounds__(256, 1) void k_lstm5(
    const __half* __restrict__ XFs, const __half* __restrict__ XBs,
    const __half* __restrict__ WBf, const __half* __restrict__ WBb,
    __half* __restrict__ HexS, unsigned int* __restrict__ flags,
    __half* __restrict__ XT) {
  int bx = blockIdx.x;          // 0..63
  int dir = bx >> 5, slice = (bx >> 1) & 15, bh = bx & 1;
  int tid = threadIdx.x;
  int lane = tid & 63, wave = tid >> 6;
  const __half* xWs = dir ? XBs : XFs;
  const __half* WB = dir ? WBb : WBf;
  __half* hexd = HexS + (size_t)dir * 256 * 16384;  // [step][bh2][sl16][b32][u16]
  unsigned int* flg = flags + (dir * 2 + bh) * 4096;  // [slice16][step256]

  __shared__ _Float16 H[32 * 266];   // [b32][u], row stride 266 f16
  __shared__ float GT[32 * 69];      // [b32][c64], row stride 69 dw

  // ---- preload B-fragments: 64 cols x 256 k (32 VGPRs)  [r22 formula]
  f16x8 bfrag[8];
  {
    int c = (slice & 1) * 64 + wave * 16 + (lane & 15);
#pragma unroll
    for (int kt = 0; kt < 8; ++kt)
      bfrag[kt] = *(const f16x8*)(
          WB + ((size_t)((slice >> 1) * 128 + c) * 256) + kt * 32 +
          (lane >> 4) * 8);
  }
  // ---- zero H
  for (int i = tid; i < 32 * 266 / 8; i += 256)
    ((f16x8*)H)[i] = (f16x8)(_Float16)0.0f;
  float cst[2];
  cst[0] = 0.0f; cst[1] = 0.0f;
  int b_own = tid >> 3;   // local batch 0..31
  int uc = tid & 7;       // 2-unit chunk within the 16-unit slice
  int bglob = bh * 32 + b_own;
  // xW base offset for this thread (constant across steps; r22 layout)
  size_t xw_off = bglob * 32 + (slice & 1) * 16 + uc * 2;
  // ---- preload xW gates for step 0
  f16x2 xwg[4];
  {
    int t0 = dir ? 255 : 0;
    const __half* xwp = xWs + ((size_t)(t0 * 8 + (slice >> 1)) * 8192) + xw_off;
#pragma unroll
    for (int g = 0; g < 4; ++g) xwg[g] = *(const f16x2*)(xwp + g * 2048);
  }
  __syncthreads();

  for (int s = 0; s < 256; ++s) {
    int t = dir ? (255 - s) : s;

    // ---- MFMA: gates[32 b, 64 c] = H[32,256] @ Wslice[256,64]
    f32x4 acc[2];
    acc[0] = (f32x4)0.0f; acc[1] = (f32x4)0.0f;
#pragma unroll
    for (int kt = 0; kt < 8; ++kt) {
      f16x8 a[2];
#pragma unroll
      for (int mt = 0; mt < 2; ++mt)
        a[mt] = *(const f16x8*)&H[(mt * 16 + (lane & 15)) * 266 + kt * 32 +
                                  (lane >> 4) * 8];
#pragma unroll
      for (int mt = 0; mt < 2; ++mt)
        acc[mt] = __builtin_amdgcn_mfma_f32_16x16x32_f16(
            a[mt], bfrag[kt], acc[mt], 0, 0, 0);
    }
    __syncthreads();  // H consumed; GT fully read (prev update)
    // ---- transpose C-layout -> GT[b32][c64]
    {
      int col = wave * 16 + (lane & 15);
#pragma unroll
      for (int mt = 0; mt < 2; ++mt)
#pragma unroll
        for (int r = 0; r < 4; ++r) {
          int b = mt * 16 + (lane >> 4) * 4 + r;
          GT[b * 69 + col] = acc[mt][r];
        }
    }
    __syncthreads();
    // ---- c/h update for own (b_own, units uc*2..uc*2+1)
    PK2 hv;
#pragma unroll
    for (int p = 0; p < 2; ++p) {
      int ul = uc * 2 + p;
      float4 g4 = *(const float4*)&GT[b_own * 69 + 4 * ul];
      float gi = g4.x + (float)xwg[0][p];
      float gf = g4.y + (float)xwg[1][p];
      float gg = g4.z + (float)xwg[2][p];
      float go = g4.w + (float)xwg[3][p];
      cst[p] = sigm(gf) * cst[p] + sigm(gi) * tanh_fast(gg);
      float hn = sigm(go) * tanh_fast(cst[p]);
      hv.h[p] = (_Float16)hn;
    }
    // own h -> LDS H (units slice*16 + uc*2)
    *(f16x2*)&H[b_own * 266 + slice * 16 + uc * 2] = hv.v;

    if (s < 255) {
      __half* hexq = hexd + (size_t)s * 16384;
      // ---- publish directly from registers (block-contiguous 1KB)
      unsigned int* dst =
          (unsigned int*)(hexq + (bh * 16 + slice) * 512 + tid * 2);
      __hip_atomic_store(dst, hv.u32, __ATOMIC_RELAXED,
                         __HIP_MEMORY_SCOPE_AGENT);
      // drain own wave's publish stores to the LLC, then block rendezvous
      asm volatile("s_waitcnt vmcnt(0)" ::: "memory");
      __syncthreads();
      if (tid == 0)
        __hip_atomic_store(&flg[(slice << 8) + s], 1u, __ATOMIC_RELAXED,
                           __HIP_MEMORY_SCOPE_AGENT);
      // XT store AFTER flag (out of the drain path)
      *(f16x2*)(XT + (size_t)((bglob << 8) + t) * 544 + dir * 256 +
                slice * 16 + uc * 2) = hv.v;
      // ---- prefetch next step's xW gates (latency hides under poll+gather)
      f16x2 xwn[4];
      {
        int tn = dir ? (254 - s) : (s + 1);
        const __half* xwp =
            xWs + ((size_t)(tn * 8 + (slice >> 1)) * 8192) + xw_off;
#pragma unroll
        for (int g = 0; g < 4; ++g) xwn[g] = *(const f16x2*)(xwp + g * 2048);
      }
      // poll the 15 peer flags in parallel (lanes 0..15); load RT paces loop
      if (tid < 16 && tid != slice) {
        while (__hip_atomic_load(&flg[(tid << 8) + s], __ATOMIC_RELAXED,
                                 __HIP_MEMORY_SCOPE_AGENT) == 0u) {}
      }
      __syncthreads();
      // ---- gather 15 peer slices for THIS batch-half (contiguous, MLP)
#pragma unroll
      for (int i = 0; i < 15; ++i) {
        int ps = i + (i >= slice ? 1 : 0);
        f16x2 pv = *(const f16x2*)(hexq + (bh * 16 + ps) * 512 + tid * 2);
        *(f16x2*)&H[b_own * 266 + ps * 16 + uc * 2] = pv;
      }
      __syncthreads();  // H complete before next step's MFMA
#pragma unroll
      for (int g = 0; g < 4; ++g) xwg[g] = xwn[g];
    } else {
      *(f16x2*)(XT + (size_t)((bglob << 8) + t) * 544 + dir * 256 +
                slice * 16 + uc * 2) = hv.v;
    }
  }
}

// ---------------- MFMA f16 dual-job tree GEMM (stages 0-2 only) ----------
__global__ __launch_bounds__(256) void k_tgemm(
    const float* __restrict__ A,
    const __half* __restrict__ BT0, float* __restrict__ Cv0, int M0,
    int band_lo0, int blog0,
    const __half* __restrict__ BT1, float* __restrict__ Cv1, int M1,
    int band_lo1, int blog1, int nb0,
    const int* __restrict__ dep_heads,
    const float* __restrict__ xWf, const float* __restrict__ c_buf) {
  __shared__ _Float16 As[128 * 40];
  __shared__ _Float16 Bs[128 * 40];
  int tid = threadIdx.x;
  int lane = tid & 63, wave = tid >> 6;
  int wm = wave & 1, wn = wave >> 1;
  int f = blockIdx.x;
  const __half* BT; float* Cv; int M, N, band_lo, blog, amode, epi;
  int bx, by;
  if (f < nb0) {
    BT = BT0; Cv = Cv0; M = M0; N = 256; band_lo = band_lo0; blog = blog0;
    amode = 1; epi = 2; bx = f & 1; by = f >> 1;
  } else {
    f -= nb0;
    BT = BT1; Cv = Cv1; M = M1; N = 768; band_lo = band_lo1; blog = blog1;
    amode = 2; epi = 0; bx = f % 6; by = f / 6;
  }
  int col0 = bx * 128, row0 = by * 128;
  int bmask = (1 << blog) - 1;

  f32x4 acc[4][4];
#pragma unroll
  for (int i = 0; i < 4; ++i)
#pragma unroll
    for (int j = 0; j < 4; ++j) acc[i][j] = (f32x4)0.0f;

  for (int kt = 0; kt < 256; kt += 32) {
    __syncthreads();
#pragma unroll
    for (int it = 0; it < 2; ++it) {
      int lin = tid + it * 256;
      int r = lin & 127, kh8 = (lin >> 7) * 8;
      int row = row0 + r;
      f16x8 va = (f16x8)(_Float16)0.0f;
      if (row < M) {
        if (amode == 1) {
          int b_ = row >> blog, t_ = band_lo + (row & bmask);
          const float* src = A + (size_t)((b_ << 8) + t_) * 256 + kt + kh8;
          float4 a4 = *(const float4*)src;
          float4 b4 = *(const float4*)(src + 4);
          va[0] = (_Float16)a4.x; va[1] = (_Float16)a4.y;
          va[2] = (_Float16)a4.z; va[3] = (_Float16)a4.w;
          va[4] = (_Float16)b4.x; va[5] = (_Float16)b4.y;
          va[6] = (_Float16)b4.z; va[7] = (_Float16)b4.w;
        } else {
          int b_ = row >> blog, p_ = band_lo + (row & bmask);
          const float* p0 = A + (size_t)((b_ << 8) + 2 * p_) * 256 + kt + kh8;
          float4 x0a = {0.0f, 0.0f, 0.0f, 0.0f};
          float4 x0b = {0.0f, 0.0f, 0.0f, 0.0f};
          if (2 * p_ != 0) {
            x0a = *(const float4*)p0;
            x0b = *(const float4*)(p0 + 4);
          }
          float4 x1a = *(const float4*)(p0 + 256);
          float4 x1b = *(const float4*)(p0 + 260);
          va[0] = (_Float16)(x0a.x + x1a.x); va[1] = (_Float16)(x0a.y + x1a.y);
          va[2] = (_Float16)(x0a.z + x1a.z); va[3] = (_Float16)(x0a.w + x1a.w);
          va[4] = (_Float16)(x0b.x + x1b.x); va[5] = (_Float16)(x0b.y + x1b.y);
          va[6] = (_Float16)(x0b.z + x1b.z); va[7] = (_Float16)(x0b.w + x1b.w);
        }
      }
      *(f16x8*)&As[r * 40 + kh8] = va;
      f16x8 vb = *(const f16x8*)(BT + (size_t)(col0 + r) * 256 + kt + kh8);
      *(f16x8*)&Bs[r * 40 + kh8] = vb;
    }
    __syncthreads();
    f16x8 af[4], bf[4];
    int kq = (lane >> 4) * 8;
#pragma unroll
    for (int mt = 0; mt < 4; ++mt)
      af[mt] = *(const f16x8*)&As[(wm * 64 + mt * 16 + (lane & 15)) * 40 + kq];
#pragma unroll
    for (int nt = 0; nt < 4; ++nt)
      bf[nt] = *(const f16x8*)&Bs[(wn * 64 + nt * 16 + (lane & 15)) * 40 + kq];
#pragma unroll
    for (int mt = 0; mt < 4; ++mt)
#pragma unroll
      for (int nt = 0; nt < 4; ++nt)
        acc[mt][nt] = __builtin_amdgcn_mfma_f32_16x16x32_f16(
            af[mt], bf[nt], acc[mt][nt], 0, 0, 0);
  }

#pragma unroll
  for (int mt = 0; mt < 4; ++mt) {
#pragma unroll
    for (int nt = 0; nt < 4; ++nt) {
      int col = col0 + wn * 64 + nt * 16 + (lane & 15);
#pragma unroll
      for (int r = 0; r < 4; ++r) {
        int row = row0 + wm * 64 + mt * 16 + (lane >> 4) * 4 + r;
        if (row >= M) continue;
        float v = acc[mt][nt][r];
        if (epi == 2) {
          int b_ = row >> blog, t_ = band_lo + (row & bmask);
          int par = dep_heads[(b_ << 8) + t_];
          float m = (par != t_) ? 1.0f : 0.0f;
          float xwv = xWf[(size_t)((b_ << 8) + par) * 256 + col];
          float cv = c_buf[(size_t)((b_ << 8) + t_) * 256 + col];
          v = sigm(v + xwv) * cv * m;
        }
        Cv[(size_t)row * N + col] = v;
      }
    }
  }
}

// ---------------- tree tail level: compile-time bounds (registers!) ------
template <int PLO, int NP>
__device__ __forceinline__ void tree_level(
    int b, int j, float* __restrict__ Hs, float* __restrict__ Cs,
    const float* __restrict__ xWiou, const float* __restrict__ xWf,
    const int* __restrict__ dep_heads,
    const float* __restrict__ Uf, const float* __restrict__ Uiou) {
  constexpr int NCH = 2 * NP;
  constexpr int C0 = 2 * PLO;
  float fd[NCH];
#pragma unroll
  for (int ci = 0; ci < NCH; ++ci) fd[ci] = 0.0f;
  for (int k = 0; k < 256; ++k) {
    float u = Uf[(size_t)k * 256 + j];
#pragma unroll
    for (int ci = 0; ci < NCH; ++ci)
      fd[ci] += Hs[(C0 + ci) * 256 + k] * u;
  }
  float io0[NP], io1[NP], io2[NP];
#pragma unroll
  for (int p = 0; p < NP; ++p) { io0[p] = 0.0f; io1[p] = 0.0f; io2[p] = 0.0f; }
  for (int k = 0; k < 256; ++k) {
    float u0 = Uiou[(size_t)k * 768 + j];
    float u1 = Uiou[(size_t)k * 768 + 256 + j];
    float u2 = Uiou[(size_t)k * 768 + 512 + j];
#pragma unroll
    for (int p = 0; p < NP; ++p) {
      constexpr bool has0 = (PLO != 0);
      int pp = PLO + p;
      float hs = Hs[(2 * pp + 1) * 256 + k];
      if (has0 || p > 0) hs += Hs[2 * pp * 256 + k];
      io0[p] += hs * u0; io1[p] += hs * u1; io2[p] += hs * u2;
    }
  }
  __syncthreads();  // all dot reads complete before parent-row writes
#pragma unroll
  for (int p = 0; p < NP; ++p) {
    int pp = PLO + p;
    size_t prow = (size_t)((b << 8) + pp);
    int ta = 2 * pp, tb = 2 * pp + 1;
    int para = dep_heads[(b << 8) + ta];
    int parb = dep_heads[(b << 8) + tb];
    float ma = (para != ta) ? 1.0f : 0.0f;
    float mb = (parb != tb) ? 1.0f : 0.0f;
    float fca = sigm(fd[2 * p] + xWf[(size_t)((b << 8) + para) * 256 + j]) *
                Cs[ta * 256 + j] * ma;
    float fcb = sigm(fd[2 * p + 1] + xWf[(size_t)((b << 8) + parb) * 256 + j]) *
                Cs[tb * 256 + j] * mb;
    float fcsum = fca + fcb;
    float iv = xWiou[prow * 768 + j] + io0[p];
    float ov = xWiou[prow * 768 + 256 + j] + io1[p];
    float uv = xWiou[prow * 768 + 512 + j] + io2[p];
    float cc = sigm(iv) * tanh_fast(uv) + fcsum;
    float hh = sigm(ov) * tanh_fast(cc);
    Cs[pp * 256 + j] = cc;
    Hs[pp * 256 + j] = hh;
  }
  __syncthreads();
}

// ---------------- tree tail: stages plo 8,4,2,1,0 in ONE kernel ----------
__global__ __launch_bounds__(256) void k_tree_tail(
    const float* __restrict__ xWiou, const float* __restrict__ xWf,
    const int* __restrict__ dep_heads,
    const float* __restrict__ Uf, const float* __restrict__ Uiou,
    float* __restrict__ h_buf, float* __restrict__ c_buf) {
  int b = blockIdx.x, j = threadIdx.x;
  __shared__ float Hs[32 * 256];
  __shared__ float Cs[32 * 256];
  for (int t = 0; t < 16; ++t) {
    Hs[t * 256 + j] = 0.0f;
    Cs[t * 256 + j] = 0.0f;
  }
  for (int t = 16; t < 32; ++t) {
    size_t row = (size_t)((b << 8) + t);
    Hs[t * 256 + j] = h_buf[row * 256 + j];
    Cs[t * 256 + j] = c_buf[row * 256 + j];
  }
  __syncthreads();
  tree_level<8, 8>(b, j, Hs, Cs, xWiou, xWf, dep_heads, Uf, Uiou);
  tree_level<4, 4>(b, j, Hs, Cs, xWiou, xWf, dep_heads, Uf, Uiou);
  tree_level<2, 2>(b, j, Hs, Cs, xWiou, xWf, dep_heads, Uf, Uiou);
  tree_level<1, 1>(b, j, Hs, Cs, xWiou, xWf, dep_heads, Uf, Uiou);
  tree_level<0, 1>(b, j, Hs, Cs, xWiou, xWf, dep_heads, Uf, Uiou);
  // write back h rows 0..15 (classifier may read any root index)
  for (int t = 0; t < 16; ++t)
    h_buf[(size_t)((b << 8) + t) * 256 + j] = Hs[t * 256 + j];
}

// ---------------- tree leaves: t in [128,256) ----------------
__global__ __launch_bounds__(256) void k_leaves(
    const float* __restrict__ xWiou, float* __restrict__ h_buf,
    float* __restrict__ c_buf) {
  int r = blockIdx.x;  // 0..8191
  int b = r >> 7, t = 128 + (r & 127);
  size_t row = (size_t)((b << 8) + t);
  int j = threadIdx.x;
  float i = xWiou[row * 768 + j];
  float o = xWiou[row * 768 + 256 + j];
  float u = xWiou[row * 768 + 512 + j];
  float c = sigm(i) * tanh_fast(u);
  float h = sigm(o) * tanh_fast(c);
  c_buf[row * 256 + j] = c;
  h_buf[row * 256 + j] = h;
}

// ---------------- tree stage update (stages 0-2 only) ----------------
__global__ __launch_bounds__(256) void k_update(
    const float* __restrict__ xWiou, const float* __restrict__ iou_lin,
    const float* __restrict__ FC, float* __restrict__ h_buf,
    float* __restrict__ c_buf, int plo, int nplog2) {
  int r = blockIdx.x, j = threadIdx.x;
  int npm = (1 << nplog2) - 1;
  int b = r >> nplog2, loc = r & npm, p = plo + loc;
  size_t row = (size_t)((b << 8) + p);
  float i = xWiou[row * 768 + j] + iou_lin[(size_t)r * 768 + j];
  float o = xWiou[row * 768 + 256 + j] + iou_lin[(size_t)r * 768 + 256 + j];
  float u = xWiou[row * 768 + 512 + j] + iou_lin[(size_t)r * 768 + 512 + j];
  int nch = 2 << nplog2;
  float fc = FC[(size_t)(b * nch + 2 * loc) * 256 + j] +
             FC[(size_t)(b * nch + 2 * loc + 1) * 256 + j];
  float c = sigm(i) * tanh_fast(u) + fc;
  float h = sigm(o) * tanh_fast(c);
  c_buf[row * 256 + j] = c;
  h_buf[row * 256 + j] = h;
}

// ---------------- classifier ----------------
__global__ __launch_bounds__(256) void k_classifier(
    const float* __restrict__ h_buf, const int* __restrict__ root_idx,
    const float* __restrict__ W1, const float* __restrict__ b1,
    const float* __restrict__ W2, const float* __restrict__ b2,
    float* __restrict__ out) {
  int b = blockIdx.x, j = threadIdx.x;
  __shared__ float hroot[256];
  __shared__ float hid[256];
  int root = root_idx[b];
  hroot[j] = h_buf[(size_t)((b << 8) + root) * 256 + j];
  __syncthreads();
  float acc = b1[j];
  for (int k = 0; k < 256; ++k) acc += hroot[k] * W1[k * 256 + j];
  hid[j] = fmaxf(acc, 0.0f);
  __syncthreads();
  if (j < 10) {
    float o = b2[j];
    for (int k = 0; k < 256; ++k) o += hid[k] * W2[k * 10 + j];
    out[b * 10 + j] = o;
  }
}

// ---------------------------------------------------------------------------
extern "C" void kernel_launch(void* const* d_in, const int* in_sizes, int n_in,
                              void* d_out, int out_size, void* d_ws,
                              size_t ws_size, hipStream_t stream) {
  (void)in_sizes; (void)n_in; (void)out_size; (void)ws_size;
  const float* tf       = (const float*)d_in[0];
  const int*   pos_ids  = (const int*)d_in[1];
  const int*   dep_ids  = (const int*)d_in[2];
  const int*   e1       = (const int*)d_in[3];
  const int*   e2       = (const int*)d_in[4];
  const int*   sdp      = (const int*)d_in[5];
  const int*   heads    = (const int*)d_in[6];
  const int*   root     = (const int*)d_in[7];
  const float* pos_tab  = (const float*)d_in[8];
  const float* dep_tab  = (const float*)d_in[9];
  const float* dist_tab = (const float*)d_in[10];
  const float* sdp_tab  = (const float*)d_in[11];
  const float* W_ft     = (const float*)d_in[12];
  const float* b_ft     = (const float*)d_in[13];
  const float* Wih_f    = (const float*)d_in[14];
  const float* Whh_f    = (const float*)d_in[15];
  const float* bl_f     = (const float*)d_in[16];
  const float* Wih_b    = (const float*)d_in[17];
  const float* Whh_b    = (const float*)d_in[18];
  const float* bl_b     = (const float*)d_in[19];
  const float* W_iou    = (const float*)d_in[20];
  const float* U_iou    = (const float*)d_in[21];
  const float* b_iou    = (const float*)d_in[22];
  const float* Wf_t     = (const float*)d_in[23];
  const float* Uf_t     = (const float*)d_in[24];
  const float* bf_t     = (const float*)d_in[25];
  const float* W1       = (const float*)d_in[26];
  const float* b1       = (const float*)d_in[27];
  const float* W2       = (const float*)d_in[28];
  const float* b2       = (const float*)d_in[29];

  // ---- workspace (lifetime-overlaid; peak 122.16 MB < proven-safe 122.7 MB)
  char* ws = (char*)d_ws;
  __half* XF    = (__half*)(ws + 0ull);            // 33.5MB  phase2->3 (staged layout)
  __half* XB    = (__half*)(ws + 33554432ull);     // 33.5MB  phase2->3 (staged layout)
  float*  XWIOU = (float*)(ws + 0ull);             // 50.3MB  phase5->6
  float*  XWF   = (float*)(ws + 50331648ull);      // 16.8MB  phase5->6
  __half* XT    = (__half*)(ws + 67108864ull);     // 17.8MB  phase3->5
  float*  FCb   = (float*)(ws + 67108864ull);      //  8.4MB  phase6
  float*  IOUL  = (float*)(ws + 75497472ull);      // 12.6MB  phase6
  float*  H     = (float*)(ws + 88080384ull);      // 16.8MB  phase6
  __half* T     = (__half*)(ws + 88080384ull);     // 16.8MB  phase1->2 (over H)
  __half* HexS  = (__half*)(ws + 88080384ull);     // 16.8MB  phase3 (over T/H)
  float*  C     = (float*)(ws + 104857600ull);     // 16.8MB  phase6 -> 121634816
  // packs live inside C region (dead before C written):
  __half* BTft  = (__half*)(ws + 104857600ull);    // 950,272
  __half* BTwhf = (__half*)(ws + 105807872ull);    // 1,048,576
  __half* BTwhb = (__half*)(ws + 106856448ull);    // 1,048,576
  __half* BTiou = (__half*)(ws + 107905024ull);    // 835,584
  __half* BTf   = (__half*)(ws + 108740608ull);    // 278,528
  __half* WBf   = (__half*)(ws + 109019136ull);    // 524,288
  __half* WBb   = (__half*)(ws + 109543424ull);    // 524,288
  unsigned int* FLG = (unsigned int*)(ws + 110198784ull);  // 65,536 (2x2x16x256)
  // tree packs (live through phase 6) placed AFTER C:
  __half* BTuiou = (__half*)(ws + 121634816ull);   // 393,216
  __half* BTuf   = (__half*)(ws + 122028032ull);   // 131,072 -> 122159104

  EmbArgs ea{tf, pos_ids, dep_ids, e1, e2, sdp, pos_tab, dep_tab, dist_tab, sdp_tab};

  // 0. merged prep: packs + zft + WB packs + flag zero + depfill + tree packs
  k_prep<<<dim3(13312), dim3(256), 0, stream>>>(
      W_ft, BTft, Wih_f, BTwhf, Wih_b, BTwhb, W_iou, BTiou, Wf_t, BTf,
      Whh_f, WBf, Whh_b, WBb, FLG, dep_ids, dep_tab, XT,
      Uf_t, BTuf, U_iou, BTuiou);

  // 1. T = tanh(embed @ W_ft + b_ft)  [f16 out, embed fused]
  k_mgemm<<<dim3(4, 128), dim3(256), 0, stream>>>(
      nullptr, BTft, b_ft, (void*)T, 512, 928, 0, 1, 1, 1, ea,
      BTft, b_ft, (void*)T, 512, 10000);
  // 2. xW_f / xW_b merged (one launch): bx<8 -> XF job, bx>=8 -> XB job
  k_mgemm<<<dim3(16, 128), dim3(256), 0, stream>>>(
      T, BTwhf, bl_f, (void*)XF, 1024, 512, 512, 0, 0, 2, ea,
      BTwhb, bl_b, (void*)XB, 1024, 8);
  // 3. BiLSTM -> XT cols [0,512)   (HexS overlays dead T; 64 blocks)
  k_lstm5<<<dim3(64), dim3(256), 0, stream>>>(XF, XB, WBf, WBb, HexS, FLG, XT);
  // 5. xWiou / xWf merged (one launch): bx<6 -> XWIOU, bx>=6 -> XWF
  k_mgemm<<<dim3(8, 128), dim3(256), 0, stream>>>(
      XT, BTiou, b_iou, (void*)XWIOU, 768, 544, 544, 0, 0, 0, ea,
      BTf, bf_t, (void*)XWF, 256, 6);
  // 6. tree: leaves, 3 big MFMA stages, then the 5-stage tail in one kernel
  k_leaves<<<dim3(8192), dim3(256), 0, stream>>>(XWIOU, H, C);
  const int plos[3] = {64, 32, 16};
  const int lgs[3]  = {6, 5, 4};
  for (int s = 0; s < 3; ++s) {
    int plo = plos[s], lg = lgs[s];
    int npar = 1 << lg;
    int Mch = 128 * npar;
    int Mp = 64 * npar;
    int nb0 = 2 * npar;                     // FCb: 2 col-blocks x npar rows
    int nb1 = 6 * ((Mp + 127) / 128);       // IOUL: 6 col-blocks x ceil rows
    k_tgemm<<<dim3(nb0 + nb1), dim3(256), 0, stream>>>(
        H, BTuf, FCb, Mch, 2 * plo, lg + 1,
        BTuiou, IOUL, Mp, plo, lg, nb0, heads, XWF, C);
    k_update<<<dim3(Mp), dim3(256), 0, stream>>>(XWIOU, IOUL, FCb, H, C, plo, lg);
  }
  k_tree_tail<<<dim3(64), dim3(256), 0, stream>>>(XWIOU, XWF, heads,
                                                  Uf_t, U_iou, H, C);
  // 7. classifier
  k_classifier<<<dim3(64), dim3(256), 0, stream>>>(H, root, W1, b1, W2, b2,
                                                   (float*)d_out);
}

// Round 18
// 1153.063 us; speedup vs baseline: 2.3450x; 1.1364x over previous
//
#include <hip/hip_runtime.h>
#include <hip/hip_fp16.h>
#include <math.h>

// ---------------------------------------------------------------------------
// RelationExtractionModel B=64,T=256. Round 27: batch-quartered thin-slice
// BiLSTM — 128 blocks = 2 dirs x 16 slices x 4 batch-quarters(16). Third
// application of the proven tile-shrink lever (r22: -0.71us/step, r26:
// -0.97us/step): 8 MFMA/wave (M=16, mt=0 formulas), 1 gate-unit/thread,
// publish 512B, gather 15x512B. r2 protocol byte-identical per (dir,qtr)
// group of 16 blocks (8 independent groups). Everything else = round 26
// (1310us verified).
// ---------------------------------------------------------------------------

typedef _Float16 f16x8 __attribute__((ext_vector_type(8)));
typedef float    f32x4 __attribute__((ext_vector_type(4)));

union PK1 { _Float16 h; unsigned short u16; };

#define LOG2E 1.44269504088896340736f

__device__ __forceinline__ float fexp2(float x) {
  return __builtin_amdgcn_exp2f(x);
}
__device__ __forceinline__ float frcp(float x) {
  return __builtin_amdgcn_rcpf(x);
}
__device__ __forceinline__ float sigm(float x) {
  return frcp(1.0f + fexp2(-LOG2E * x));
}
__device__ __forceinline__ float tanh_fast(float x) {
  return 1.0f - 2.0f * frcp(1.0f + fexp2(2.0f * LOG2E * x));
}

struct EmbArgs {
  const float* tf; const int* pos_ids; const int* dep_ids;
  const int* e1; const int* e2; const int* sdp;
  const float* pos_tab; const float* dep_tab; const float* dist_tab;
  const float* sdp_tab;
};

// ---------------- merged prep: packs + zft + WB packs + flag zero + depfill
// ranges (all multiples of 256; formulas verbatim from proven kernels):
//  BTft 466944 | zft 8192 | BTwhf 524288 | BTwhb 524288 | BTiou 417792 |
//  BTf 139264 | WBf 262144 | WBb 262144 | FLG 32768 | depfill 524288 |
//  BTuf 65536 | BTuiou 196608   -> total 3424256 = 13376 blocks x 256
__global__ __launch_bounds__(256) void k_prep(
    const float* __restrict__ W_ft, __half* __restrict__ BTft,
    const float* __restrict__ Wih_f, __half* __restrict__ BTwhf,
    const float* __restrict__ Wih_b, __half* __restrict__ BTwhb,
    const float* __restrict__ W_iou, __half* __restrict__ BTiou,
    const float* __restrict__ Wf_t, __half* __restrict__ BTf,
    const float* __restrict__ Whh_f, __half* __restrict__ WBf,
    const float* __restrict__ Whh_b, __half* __restrict__ WBb,
    unsigned int* __restrict__ FLG,
    const int* __restrict__ dep_ids, const float* __restrict__ dep_tab,
    __half* __restrict__ XT,
    const float* __restrict__ Uf, __half* __restrict__ BTuf,
    const float* __restrict__ Uiou, __half* __restrict__ BTuiou) {
  int e = blockIdx.x * 256 + threadIdx.x;
  if (e < 466944) {                       // BTft: n fastest (coalesced read)
    int n = e & 511, k = e >> 9;          // k<912
    BTft[(size_t)n * 928 + k] = __float2half_rn(W_ft[(size_t)k * 512 + n]);
  } else if ((e -= 466944) < 8192) {      // zft pad cols [912,928)
    int n = e >> 4, kk = e & 15;
    BTft[(size_t)n * 928 + 912 + kk] = __float2half_rn(0.0f);
  } else if ((e -= 8192) < 524288) {      // BTwhf
    int n = e & 1023, k = e >> 10;        // k<512
    BTwhf[(size_t)n * 512 + k] = __float2half_rn(Wih_f[(size_t)k * 1024 + n]);
  } else if ((e -= 524288) < 524288) {    // BTwhb
    int n = e & 1023, k = e >> 10;
    BTwhb[(size_t)n * 512 + k] = __float2half_rn(Wih_b[(size_t)k * 1024 + n]);
  } else if ((e -= 524288) < 417792) {    // BTiou: N=768, K=544
    int n = e % 768, k = e / 768;
    BTiou[(size_t)n * 544 + k] = __float2half_rn(W_iou[(size_t)k * 768 + n]);
  } else if ((e -= 417792) < 139264) {    // BTf: N=256, K=544
    int n = e & 255, k = e >> 8;
    BTf[(size_t)n * 544 + k] = __float2half_rn(Wf_t[(size_t)k * 256 + n]);
  } else if ((e -= 139264) < 262144) {    // WBf  [r11 k_packWB verbatim]
    int k = e & 255, c = (e >> 8) & 127, j = e >> 15;
    int col = (c & 3) * 256 + j * 32 + (c >> 2);
    WBf[e] = __float2half_rn(Whh_f[(size_t)k * 1024 + col]);
  } else if ((e -= 262144) < 262144) {    // WBb
    int k = e & 255, c = (e >> 8) & 127, j = e >> 15;
    int col = (c & 3) * 256 + j * 32 + (c >> 2);
    WBb[e] = __float2half_rn(Whh_b[(size_t)k * 1024 + col]);
  } else if ((e -= 262144) < 32768) {     // flag zero [dir2][bq4][slice16][256]
    FLG[e] = 0u;
  } else if ((e -= 32768) < 524288) {     // depfill -> XT cols [512,544)
    int row = e >> 5, kk = e & 31;
    XT[(size_t)row * 544 + 512 + kk] =
        __float2half_rn(dep_tab[dep_ids[row] * 32 + kk]);
  } else if ((e -= 524288) < 65536) {     // BTuf: N=256, K=256
    int n = e & 255, k = e >> 8;
    BTuf[(size_t)n * 256 + k] = __float2half_rn(Uf[(size_t)k * 256 + n]);
  } else {                                // BTuiou: N=768, K=256
    e -= 65536;
    int n = e % 768, k = e / 768;
    BTuiou[(size_t)n * 256 + k] = __float2half_rn(Uiou[(size_t)k * 768 + n]);
  }
}

// ---------------- MFMA f16 GEMM (dual-job via split_bx) ----------------
// out_mode: 0 = f32 row-major, 1 = f16 row-major, 2 = f16 LSTM staging layout
// [t][slice8][gate4][b64][u32] (M must be 16384 rows = b*256+t, N=1024).
// Blocks with blockIdx.x >= split_bx run the secondary job (BT2/bias2/out2/N2).
__global__ __launch_bounds__(256) void k_mgemm(
    const __half* __restrict__ A16, const __half* __restrict__ BT,
    const float* __restrict__ bias, void* __restrict__ out,
    int N, int K, int lda, int a_embed, int act_tanh, int out_mode,
    EmbArgs ea,
    const __half* __restrict__ BT2, const float* __restrict__ bias2,
    void* __restrict__ out2, int N2, int split_bx) {
  __shared__ _Float16 As[128 * 40];
  __shared__ _Float16 Bs[128 * 40];
  int tid = threadIdx.x;
  int lane = tid & 63, wave = tid >> 6;
  int wm = wave & 1, wn = wave >> 1;
  int bxx = blockIdx.x;
  const __half* BTp = BT; const float* biasp = bias;
  void* outp = out; int Np = N;
  if (bxx >= split_bx) {
    bxx -= split_bx; BTp = BT2; biasp = bias2; outp = out2; Np = N2;
  }
  int col0 = bxx * 128, row0 = blockIdx.y * 128;

  f32x4 acc[4][4];
#pragma unroll
  for (int i = 0; i < 4; ++i)
#pragma unroll
    for (int j = 0; j < 4; ++j) acc[i][j] = (f32x4)0.0f;

  for (int kt = 0; kt < K; kt += 32) {
    __syncthreads();
#pragma unroll
    for (int it = 0; it < 2; ++it) {
      int lin = tid + it * 256;
      int r = lin & 127, kh8 = (lin >> 7) * 8;
      f16x8 va;
      if (!a_embed) {
        va = *(const f16x8*)(A16 + (size_t)(row0 + r) * lda + kt + kh8);
      } else {
        int row = row0 + r;
        int k0 = kt + kh8;
        if (k0 >= 912) {
          va = (f16x8)(_Float16)0.0f;
        } else {
          const float* src;
          if (k0 < 768) {
            src = ea.tf + (size_t)row * 768 + k0;
          } else {
            int b_ = row >> 8, t_ = row & 255;
            if (k0 < 800) src = ea.pos_tab + ea.pos_ids[row] * 32 + (k0 - 768);
            else if (k0 < 832) src = ea.dep_tab + ea.dep_ids[row] * 32 + (k0 - 800);
            else if (k0 < 864) {
              int d = t_ - ea.e1[b_] + 10; d = d < 0 ? 0 : (d > 20 ? 20 : d);
              src = ea.dist_tab + d * 32 + (k0 - 832);
            } else if (k0 < 896) {
              int d = t_ - ea.e2[b_] + 10; d = d < 0 ? 0 : (d > 20 ? 20 : d);
              src = ea.dist_tab + d * 32 + (k0 - 864);
            } else {
              src = ea.sdp_tab + ea.sdp[row] * 16 + (k0 - 896);
            }
          }
          float4 a = *(const float4*)src;
          float4 b2 = *(const float4*)(src + 4);
          va[0] = (_Float16)a.x;  va[1] = (_Float16)a.y;
          va[2] = (_Float16)a.z;  va[3] = (_Float16)a.w;
          va[4] = (_Float16)b2.x; va[5] = (_Float16)b2.y;
          va[6] = (_Float16)b2.z; va[7] = (_Float16)b2.w;
        }
      }
      *(f16x8*)&As[r * 40 + kh8] = va;
      f16x8 vb = *(const f16x8*)(BTp + (size_t)(col0 + r) * K + kt + kh8);
      *(f16x8*)&Bs[r * 40 + kh8] = vb;
    }
    __syncthreads();
    f16x8 af[4], bf[4];
    int kq = (lane >> 4) * 8;
#pragma unroll
    for (int mt = 0; mt < 4; ++mt)
      af[mt] = *(const f16x8*)&As[(wm * 64 + mt * 16 + (lane & 15)) * 40 + kq];
#pragma unroll
    for (int nt = 0; nt < 4; ++nt)
      bf[nt] = *(const f16x8*)&Bs[(wn * 64 + nt * 16 + (lane & 15)) * 40 + kq];
#pragma unroll
    for (int mt = 0; mt < 4; ++mt)
#pragma unroll
      for (int nt = 0; nt < 4; ++nt)
        acc[mt][nt] = __builtin_amdgcn_mfma_f32_16x16x32_f16(
            af[mt], bf[nt], acc[mt][nt], 0, 0, 0);
  }

#pragma unroll
  for (int mt = 0; mt < 4; ++mt) {
#pragma unroll
    for (int nt = 0; nt < 4; ++nt) {
      int col = col0 + wn * 64 + nt * 16 + (lane & 15);
      float bv = biasp[col];
#pragma unroll
      for (int r = 0; r < 4; ++r) {
        int row = row0 + wm * 64 + mt * 16 + (lane >> 4) * 4 + r;
        float v = acc[mt][nt][r] + bv;
        if (act_tanh) v = tanh_fast(v);
        if (out_mode == 0) {
          ((float*)outp)[(size_t)row * Np + col] = v;
        } else if (out_mode == 1) {
          ((__half*)outp)[(size_t)row * Np + col] = __float2half_rn(v);
        } else {
          // LSTM staging: [t][slice8][gate4][b][32 units]
          int b_ = row >> 8, t_ = row & 255;
          int g_ = col >> 8, u_ = col & 255;
          int sl = u_ >> 5, ul = u_ & 31;
          ((__half*)outp)[((((size_t)(t_ * 8 + sl) * 4 + g_) * 64 + b_) * 32) + ul] =
              __float2half_rn(v);
        }
      }
    }
  }
}

// ---------------- BiLSTM v17: 128 blocks = 2 dir x 16 slice x 4 quarter ---
// 16 units/slice, 16 batches/block. r2 protocol per (dir,qtr) group of 16
// blocks (8 independent groups). 8 MFMA/wave (M=16, mt=0 formulas), 1
// gate-unit/thread. Busy-poll, xW prefetch under the rendezvous.
__global__ __launch_bounds__(256, 1) void k_lstm6(
    const __half* __restrict__ XFs, const __half* __restrict__ XBs,
    const __half* __restrict__ WBf, const __half* __restrict__ WBb,
    __half* __restrict__ HexS, unsigned int* __restrict__ flags,
    __half* __restrict__ XT) {
  int bx = blockIdx.x;          // 0..127
  int dir = bx >> 6, slice = (bx >> 2) & 15, bq = bx & 3;
  int tid = threadIdx.x;
  int lane = tid & 63, wave = tid >> 6;
  const __half* xWs = dir ? XBs : XFs;
  const __half* WB = dir ? WBb : WBf;
  __half* hexd = HexS + (size_t)dir * 256 * 16384;  // [step][bq4][sl16][b16][u16]
  unsigned int* flg = flags + (dir * 4 + bq) * 4096;  // [slice16][step256]

  __shared__ _Float16 H[16 * 266];   // [b16][u], row stride 266 f16
  __shared__ float GT[16 * 69];      // [b16][c64], row stride 69 dw

  // ---- preload B-fragments: 64 cols x 256 k (32 VGPRs)  [r22 formula]
  f16x8 bfrag[8];
  {
    int c = (slice & 1) * 64 + wave * 16 + (lane & 15);
#pragma unroll
    for (int kt = 0; kt < 8; ++kt)
      bfrag[kt] = *(const f16x8*)(
          WB + ((size_t)((slice >> 1) * 128 + c) * 256) + kt * 32 +
          (lane >> 4) * 8);
  }
  // ---- zero H
  for (int i = tid; i < 16 * 266 / 8; i += 256)
    ((f16x8*)H)[i] = (f16x8)(_Float16)0.0f;
  float cst = 0.0f;
  int b_own = tid >> 4;   // local batch 0..15
  int uc = tid & 15;      // single unit within the 16-unit slice
  int bglob = bq * 16 + b_own;
  // xW offset for this thread (constant across steps; r22 staging layout)
  size_t xw_off = bglob * 32 + (slice & 1) * 16 + uc;
  // ---- preload xW gates for step 0
  float xwg[4];
  {
    int t0 = dir ? 255 : 0;
    const __half* xwp = xWs + ((size_t)(t0 * 8 + (slice >> 1)) * 8192) + xw_off;
#pragma unroll
    for (int g = 0; g < 4; ++g) xwg[g] = __half2float(xwp[g * 2048]);
  }
  __syncthreads();

  for (int s = 0; s < 256; ++s) {
    int t = dir ? (255 - s) : s;

    // ---- MFMA: gates[16 b, 64 c] = H[16,256] @ Wslice[256,64]
    f32x4 acc = (f32x4)0.0f;
#pragma unroll
    for (int kt = 0; kt < 8; ++kt) {
      f16x8 a = *(const f16x8*)&H[(lane & 15) * 266 + kt * 32 +
                                  (lane >> 4) * 8];
      acc = __builtin_amdgcn_mfma_f32_16x16x32_f16(a, bfrag[kt], acc, 0, 0, 0);
    }
    __syncthreads();  // H consumed; GT fully read (prev update)
    // ---- transpose C-layout -> GT[b16][c64]  (mt=0 formula)
    {
      int col = wave * 16 + (lane & 15);
#pragma unroll
      for (int r = 0; r < 4; ++r) {
        int b = (lane >> 4) * 4 + r;
        GT[b * 69 + col] = acc[r];
      }
    }
    __syncthreads();
    // ---- c/h update for own (b_own, unit uc)
    float4 g4 = *(const float4*)&GT[b_own * 69 + 4 * uc];
    float gi = g4.x + xwg[0];
    float gf = g4.y + xwg[1];
    float gg = g4.z + xwg[2];
    float go = g4.w + xwg[3];
    cst = sigm(gf) * cst + sigm(gi) * tanh_fast(gg);
    float hn = sigm(go) * tanh_fast(cst);
    PK1 hv; hv.h = (_Float16)hn;
    // own h -> LDS H (unit slice*16 + uc)
    H[b_own * 266 + slice * 16 + uc] = hv.h;

    if (s < 255) {
      __half* hexq = hexd + (size_t)s * 16384;
      // ---- publish directly from registers (block-contiguous 512B)
      unsigned short* dst =
          (unsigned short*)(hexq + (bq * 16 + slice) * 256 + tid);
      __hip_atomic_store(dst, hv.u16, __ATOMIC_RELAXED,
                         __HIP_MEMORY_SCOPE_AGENT);
      // drain own wave's publish stores to the LLC, then block rendezvous
      asm volatile("s_waitcnt vmcnt(0)" ::: "memory");
      __syncthreads();
      if (tid == 0)
        __hip_atomic_store(&flg[(slice << 8) + s], 1u, __ATOMIC_RELAXED,
                           __HIP_MEMORY_SCOPE_AGENT);
      // XT store AFTER flag (out of the drain path)
      XT[(size_t)((bglob << 8) + t) * 544 + dir * 256 + slice * 16 + uc] =
          *(__half*)&hv.h;
      // ---- prefetch next step's xW gates (latency hides under poll+gather)
      float xwn[4];
      {
        int tn = dir ? (254 - s) : (s + 1);
        const __half* xwp =
            xWs + ((size_t)(tn * 8 + (slice >> 1)) * 8192) + xw_off;
#pragma unroll
        for (int g = 0; g < 4; ++g) xwn[g] = __half2float(xwp[g * 2048]);
      }
      // poll the 15 peer flags in parallel (lanes 0..15); load RT paces loop
      if (tid < 16 && tid != slice) {
        while (__hip_atomic_load(&flg[(tid << 8) + s], __ATOMIC_RELAXED,
                                 __HIP_MEMORY_SCOPE_AGENT) == 0u) {}
      }
      __syncthreads();
      // ---- gather 15 peer slices for THIS quarter (step-unique, MLP)
#pragma unroll
      for (int i = 0; i < 15; ++i) {
        int ps = i + (i >= slice ? 1 : 0);
        __half pv = hexq[(bq * 16 + ps) * 256 + tid];
        H[b_own * 266 + ps * 16 + uc] = *(_Float16*)&pv;
      }
      __syncthreads();  // H complete before next step's MFMA
#pragma unroll
      for (int g = 0; g < 4; ++g) xwg[g] = xwn[g];
    } else {
      XT[(size_t)((bglob << 8) + t) * 544 + dir * 256 + slice * 16 + uc] =
          *(__half*)&hv.h;
    }
  }
}

// ---------------- MFMA f16 dual-job tree GEMM (stages 0-2 only) ----------
__global__ __launch_bounds__(256) void k_tgemm(
    const float* __restrict__ A,
    const __half* __restrict__ BT0, float* __restrict__ Cv0, int M0,
    int band_lo0, int blog0,
    const __half* __restrict__ BT1, float* __restrict__ Cv1, int M1,
    int band_lo1, int blog1, int nb0,
    const int* __restrict__ dep_heads,
    const float* __restrict__ xWf, const float* __restrict__ c_buf) {
  __shared__ _Float16 As[128 * 40];
  __shared__ _Float16 Bs[128 * 40];
  int tid = threadIdx.x;
  int lane = tid & 63, wave = tid >> 6;
  int wm = wave & 1, wn = wave >> 1;
  int f = blockIdx.x;
  const __half* BT; float* Cv; int M, N, band_lo, blog, amode, epi;
  int bx, by;
  if (f < nb0) {
    BT = BT0; Cv = Cv0; M = M0; N = 256; band_lo = band_lo0; blog = blog0;
    amode = 1; epi = 2; bx = f & 1; by = f >> 1;
  } else {
    f -= nb0;
    BT = BT1; Cv = Cv1; M = M1; N = 768; band_lo = band_lo1; blog = blog1;
    amode = 2; epi = 0; bx = f % 6; by = f / 6;
  }
  int col0 = bx * 128, row0 = by * 128;
  int bmask = (1 << blog) - 1;

  f32x4 acc[4][4];
#pragma unroll
  for (int i = 0; i < 4; ++i)
#pragma unroll
    for (int j = 0; j < 4; ++j) acc[i][j] = (f32x4)0.0f;

  for (int kt = 0; kt < 256; kt += 32) {
    __syncthreads();
#pragma unroll
    for (int it = 0; it < 2; ++it) {
      int lin = tid + it * 256;
      int r = lin & 127, kh8 = (lin >> 7) * 8;
      int row = row0 + r;
      f16x8 va = (f16x8)(_Float16)0.0f;
      if (row < M) {
        if (amode == 1) {
          int b_ = row >> blog, t_ = band_lo + (row & bmask);
          const float* src = A + (size_t)((b_ << 8) + t_) * 256 + kt + kh8;
          float4 a4 = *(const float4*)src;
          float4 b4 = *(const float4*)(src + 4);
          va[0] = (_Float16)a4.x; va[1] = (_Float16)a4.y;
          va[2] = (_Float16)a4.z; va[3] = (_Float16)a4.w;
          va[4] = (_Float16)b4.x; va[5] = (_Float16)b4.y;
          va[6] = (_Float16)b4.z; va[7] = (_Float16)b4.w;
        } else {
          int b_ = row >> blog, p_ = band_lo + (row & bmask);
          const float* p0 = A + (size_t)((b_ << 8) + 2 * p_) * 256 + kt + kh8;
          float4 x0a = {0.0f, 0.0f, 0.0f, 0.0f};
          float4 x0b = {0.0f, 0.0f, 0.0f, 0.0f};
          if (2 * p_ != 0) {
            x0a = *(const float4*)p0;
            x0b = *(const float4*)(p0 + 4);
          }
          float4 x1a = *(const float4*)(p0 + 256);
          float4 x1b = *(const float4*)(p0 + 260);
          va[0] = (_Float16)(x0a.x + x1a.x); va[1] = (_Float16)(x0a.y + x1a.y);
          va[2] = (_Float16)(x0a.z + x1a.z); va[3] = (_Float16)(x0a.w + x1a.w);
          va[4] = (_Float16)(x0b.x + x1b.x); va[5] = (_Float16)(x0b.y + x1b.y);
          va[6] = (_Float16)(x0b.z + x1b.z); va[7] = (_Float16)(x0b.w + x1b.w);
        }
      }
      *(f16x8*)&As[r * 40 + kh8] = va;
      f16x8 vb = *(const f16x8*)(BT + (size_t)(col0 + r) * 256 + kt + kh8);
      *(f16x8*)&Bs[r * 40 + kh8] = vb;
    }
    __syncthreads();
    f16x8 af[4], bf[4];
    int kq = (lane >> 4) * 8;
#pragma unroll
    for (int mt = 0; mt < 4; ++mt)
      af[mt] = *(const f16x8*)&As[(wm * 64 + mt * 16 + (lane & 15)) * 40 + kq];
#pragma unroll
    for (int nt = 0; nt < 4; ++nt)
      bf[nt] = *(const f16x8*)&Bs[(wn * 64 + nt * 16 + (lane & 15)) * 40 + kq];
#pragma unroll
    for (int mt = 0; mt < 4; ++mt)
#pragma unroll
      for (int nt = 0; nt < 4; ++nt)
        acc[mt][nt] = __builtin_amdgcn_mfma_f32_16x16x32_f16(
            af[mt], bf[nt], acc[mt][nt], 0, 0, 0);
  }

#pragma unroll
  for (int mt = 0; mt < 4; ++mt) {
#pragma unroll
    for (int nt = 0; nt < 4; ++nt) {
      int col = col0 + wn * 64 + nt * 16 + (lane & 15);
#pragma unroll
      for (int r = 0; r < 4; ++r) {
        int row = row0 + wm * 64 + mt * 16 + (lane >> 4) * 4 + r;
        if (row >= M) continue;
        float v = acc[mt][nt][r];
        if (epi == 2) {
          int b_ = row >> blog, t_ = band_lo + (row & bmask);
          int par = dep_heads[(b_ << 8) + t_];
          float m = (par != t_) ? 1.0f : 0.0f;
          float xwv = xWf[(size_t)((b_ << 8) + par) * 256 + col];
          float cv = c_buf[(size_t)((b_ << 8) + t_) * 256 + col];
          v = sigm(v + xwv) * cv * m;
        }
        Cv[(size_t)row * N + col] = v;
      }
    }
  }
}

// ---------------- tree tail level: compile-time bounds (registers!) ------
template <int PLO, int NP>
__device__ __forceinline__ void tree_level(
    int b, int j, float* __restrict__ Hs, float* __restrict__ Cs,
    const float* __restrict__ xWiou, const float* __restrict__ xWf,
    const int* __restrict__ dep_heads,
    const float* __restrict__ Uf, const float* __restrict__ Uiou) {
  constexpr int NCH = 2 * NP;
  constexpr int C0 = 2 * PLO;
  float fd[NCH];
#pragma unroll
  for (int ci = 0; ci < NCH; ++ci) fd[ci] = 0.0f;
  for (int k = 0; k < 256; ++k) {
    float u = Uf[(size_t)k * 256 + j];
#pragma unroll
    for (int ci = 0; ci < NCH; ++ci)
      fd[ci] += Hs[(C0 + ci) * 256 + k] * u;
  }
  float io0[NP], io1[NP], io2[NP];
#pragma unroll
  for (int p = 0; p < NP; ++p) { io0[p] = 0.0f; io1[p] = 0.0f; io2[p] = 0.0f; }
  for (int k = 0; k < 256; ++k) {
    float u0 = Uiou[(size_t)k * 768 + j];
    float u1 = Uiou[(size_t)k * 768 + 256 + j];
    float u2 = Uiou[(size_t)k * 768 + 512 + j];
#pragma unroll
    for (int p = 0; p < NP; ++p) {
      constexpr bool has0 = (PLO != 0);
      int pp = PLO + p;
      float hs = Hs[(2 * pp + 1) * 256 + k];
      if (has0 || p > 0) hs += Hs[2 * pp * 256 + k];
      io0[p] += hs * u0; io1[p] += hs * u1; io2[p] += hs * u2;
    }
  }
  __syncthreads();  // all dot reads complete before parent-row writes
#pragma unroll
  for (int p = 0; p < NP; ++p) {
    int pp = PLO + p;
    size_t prow = (size_t)((b << 8) + pp);
    int ta = 2 * pp, tb = 2 * pp + 1;
    int para = dep_heads[(b << 8) + ta];
    int parb = dep_heads[(b << 8) + tb];
    float ma = (para != ta) ? 1.0f : 0.0f;
    float mb = (parb != tb) ? 1.0f : 0.0f;
    float fca = sigm(fd[2 * p] + xWf[(size_t)((b << 8) + para) * 256 + j]) *
                Cs[ta * 256 + j] * ma;
    float fcb = sigm(fd[2 * p + 1] + xWf[(size_t)((b << 8) + parb) * 256 + j]) *
                Cs[tb * 256 + j] * mb;
    float fcsum = fca + fcb;
    float iv = xWiou[prow * 768 + j] + io0[p];
    float ov = xWiou[prow * 768 + 256 + j] + io1[p];
    float uv = xWiou[prow * 768 + 512 + j] + io2[p];
    float cc = sigm(iv) * tanh_fast(uv) + fcsum;
    float hh = sigm(ov) * tanh_fast(cc);
    Cs[pp * 256 + j] = cc;
    Hs[pp * 256 + j] = hh;
  }
  __syncthreads();
}

// ---------------- tree tail: stages plo 8,4,2,1,0 in ONE kernel ----------
__global__ __launch_bounds__(256) void k_tree_tail(
    const float* __restrict__ xWiou, const float* __restrict__ xWf,
    const int* __restrict__ dep_heads,
    const float* __restrict__ Uf, const float* __restrict__ Uiou,
    float* __restrict__ h_buf, float* __restrict__ c_buf) {
  int b = blockIdx.x, j = threadIdx.x;
  __shared__ float Hs[32 * 256];
  __shared__ float Cs[32 * 256];
  for (int t = 0; t < 16; ++t) {
    Hs[t * 256 + j] = 0.0f;
    Cs[t * 256 + j] = 0.0f;
  }
  for (int t = 16; t < 32; ++t) {
    size_t row = (size_t)((b << 8) + t);
    Hs[t * 256 + j] = h_buf[row * 256 + j];
    Cs[t * 256 + j] = c_buf[row * 256 + j];
  }
  __syncthreads();
  tree_level<8, 8>(b, j, Hs, Cs, xWiou, xWf, dep_heads, Uf, Uiou);
  tree_level<4, 4>(b, j, Hs, Cs, xWiou, xWf, dep_heads, Uf, Uiou);
  tree_level<2, 2>(b, j, Hs, Cs, xWiou, xWf, dep_heads, Uf, Uiou);
  tree_level<1, 1>(b, j, Hs, Cs, xWiou, xWf, dep_heads, Uf, Uiou);
  tree_level<0, 1>(b, j, Hs, Cs, xWiou, xWf, dep_heads, Uf, Uiou);
  // write back h rows 0..15 (classifier may read any root index)
  for (int t = 0; t < 16; ++t)
    h_buf[(size_t)((b << 8) + t) * 256 + j] = Hs[t * 256 + j];
}

// ---------------- tree leaves: t in [128,256) ----------------
__global__ __launch_bounds__(256) void k_leaves(
    const float* __restrict__ xWiou, float* __restrict__ h_buf,
    float* __restrict__ c_buf) {
  int r = blockIdx.x;  // 0..8191
  int b = r >> 7, t = 128 + (r & 127);
  size_t row = (size_t)((b << 8) + t);
  int j = threadIdx.x;
  float i = xWiou[row * 768 + j];
  float o = xWiou[row * 768 + 256 + j];
  float u = xWiou[row * 768 + 512 + j];
  float c = sigm(i) * tanh_fast(u);
  float h = sigm(o) * tanh_fast(c);
  c_buf[row * 256 + j] = c;
  h_buf[row * 256 + j] = h;
}

// ---------------- tree stage update (stages 0-2 only) ----------------
__global__ __launch_bounds__(256) void k_update(
    const float* __restrict__ xWiou, const float* __restrict__ iou_lin,
    const float* __restrict__ FC, float* __restrict__ h_buf,
    float* __restrict__ c_buf, int plo, int nplog2) {
  int r = blockIdx.x, j = threadIdx.x;
  int npm = (1 << nplog2) - 1;
  int b = r >> nplog2, loc = r & npm, p = plo + loc;
  size_t row = (size_t)((b << 8) + p);
  float i = xWiou[row * 768 + j] + iou_lin[(size_t)r * 768 + j];
  float o = xWiou[row * 768 + 256 + j] + iou_lin[(size_t)r * 768 + 256 + j];
  float u = xWiou[row * 768 + 512 + j] + iou_lin[(size_t)r * 768 + 512 + j];
  int nch = 2 << nplog2;
  float fc = FC[(size_t)(b * nch + 2 * loc) * 256 + j] +
             FC[(size_t)(b * nch + 2 * loc + 1) * 256 + j];
  float c = sigm(i) * tanh_fast(u) + fc;
  float h = sigm(o) * tanh_fast(c);
  c_buf[row * 256 + j] = c;
  h_buf[row * 256 + j] = h;
}

// ---------------- classifier ----------------
__global__ __launch_bounds__(256) void k_classifier(
    const float* __restrict__ h_buf, const int* __restrict__ root_idx,
    const float* __restrict__ W1, const float* __restrict__ b1,
    const float* __restrict__ W2, const float* __restrict__ b2,
    float* __restrict__ out) {
  int b = blockIdx.x, j = threadIdx.x;
  __shared__ float hroot[256];
  __shared__ float hid[256];
  int root = root_idx[b];
  hroot[j] = h_buf[(size_t)((b << 8) + root) * 256 + j];
  __syncthreads();
  float acc = b1[j];
  for (int k = 0; k < 256; ++k) acc += hroot[k] * W1[k * 256 + j];
  hid[j] = fmaxf(acc, 0.0f);
  __syncthreads();
  if (j < 10) {
    float o = b2[j];
    for (int k = 0; k < 256; ++k) o += hid[k] * W2[k * 10 + j];
    out[b * 10 + j] = o;
  }
}

// ---------------------------------------------------------------------------
extern "C" void kernel_launch(void* const* d_in, const int* in_sizes, int n_in,
                              void* d_out, int out_size, void* d_ws,
                              size_t ws_size, hipStream_t stream) {
  (void)in_sizes; (void)n_in; (void)out_size; (void)ws_size;
  const float* tf       = (const float*)d_in[0];
  const int*   pos_ids  = (const int*)d_in[1];
  const int*   dep_ids  = (const int*)d_in[2];
  const int*   e1       = (const int*)d_in[3];
  const int*   e2       = (const int*)d_in[4];
  const int*   sdp      = (const int*)d_in[5];
  const int*   heads    = (const int*)d_in[6];
  const int*   root     = (const int*)d_in[7];
  const float* pos_tab  = (const float*)d_in[8];
  const float* dep_tab  = (const float*)d_in[9];
  const float* dist_tab = (const float*)d_in[10];
  const float* sdp_tab  = (const float*)d_in[11];
  const float* W_ft     = (const float*)d_in[12];
  const float* b_ft     = (const float*)d_in[13];
  const float* Wih_f    = (const float*)d_in[14];
  const float* Whh_f    = (const float*)d_in[15];
  const float* bl_f     = (const float*)d_in[16];
  const float* Wih_b    = (const float*)d_in[17];
  const float* Whh_b    = (const float*)d_in[18];
  const float* bl_b     = (const float*)d_in[19];
  const float* W_iou    = (const float*)d_in[20];
  const float* U_iou    = (const float*)d_in[21];
  const float* b_iou    = (const float*)d_in[22];
  const float* Wf_t     = (const float*)d_in[23];
  const float* Uf_t     = (const float*)d_in[24];
  const float* bf_t     = (const float*)d_in[25];
  const float* W1       = (const float*)d_in[26];
  const float* b1       = (const float*)d_in[27];
  const float* W2       = (const float*)d_in[28];
  const float* b2       = (const float*)d_in[29];

  // ---- workspace (lifetime-overlaid; peak 122.16 MB < proven-safe 122.7 MB)
  char* ws = (char*)d_ws;
  __half* XF    = (__half*)(ws + 0ull);            // 33.5MB  phase2->3 (staged layout)
  __half* XB    = (__half*)(ws + 33554432ull);     // 33.5MB  phase2->3 (staged layout)
  float*  XWIOU = (float*)(ws + 0ull);             // 50.3MB  phase5->6
  float*  XWF   = (float*)(ws + 50331648ull);      // 16.8MB  phase5->6
  __half* XT    = (__half*)(ws + 67108864ull);     // 17.8MB  phase3->5
  float*  FCb   = (float*)(ws + 67108864ull);      //  8.4MB  phase6
  float*  IOUL  = (float*)(ws + 75497472ull);      // 12.6MB  phase6
  float*  H     = (float*)(ws + 88080384ull);      // 16.8MB  phase6
  __half* T     = (__half*)(ws + 88080384ull);     // 16.8MB  phase1->2 (over H)
  __half* HexS  = (__half*)(ws + 88080384ull);     // 16.8MB  phase3 (over T/H)
  float*  C     = (float*)(ws + 104857600ull);     // 16.8MB  phase6 -> 121634816
  // packs live inside C region (dead before C written):
  __half* BTft  = (__half*)(ws + 104857600ull);    // 950,272
  __half* BTwhf = (__half*)(ws + 105807872ull);    // 1,048,576
  __half* BTwhb = (__half*)(ws + 106856448ull);    // 1,048,576
  __half* BTiou = (__half*)(ws + 107905024ull);    // 835,584
  __half* BTf   = (__half*)(ws + 108740608ull);    // 278,528
  __half* WBf   = (__half*)(ws + 109019136ull);    // 524,288
  __half* WBb   = (__half*)(ws + 109543424ull);    // 524,288
  unsigned int* FLG = (unsigned int*)(ws + 110198784ull);  // 131,072 (2x4x16x256)
  // tree packs (live through phase 6) placed AFTER C:
  __half* BTuiou = (__half*)(ws + 121634816ull);   // 393,216
  __half* BTuf   = (__half*)(ws + 122028032ull);   // 131,072 -> 122159104

  EmbArgs ea{tf, pos_ids, dep_ids, e1, e2, sdp, pos_tab, dep_tab, dist_tab, sdp_tab};

  // 0. merged prep: packs + zft + WB packs + flag zero + depfill + tree packs
  k_prep<<<dim3(13376), dim3(256), 0, stream>>>(
      W_ft, BTft, Wih_f, BTwhf, Wih_b, BTwhb, W_iou, BTiou, Wf_t, BTf,
      Whh_f, WBf, Whh_b, WBb, FLG, dep_ids, dep_tab, XT,
      Uf_t, BTuf, U_iou, BTuiou);

  // 1. T = tanh(embed @ W_ft + b_ft)  [f16 out, embed fused]
  k_mgemm<<<dim3(4, 128), dim3(256), 0, stream>>>(
      nullptr, BTft, b_ft, (void*)T, 512, 928, 0, 1, 1, 1, ea,
      BTft, b_ft, (void*)T, 512, 10000);
  // 2. xW_f / xW_b merged (one launch): bx<8 -> XF job, bx>=8 -> XB job
  k_mgemm<<<dim3(16, 128), dim3(256), 0, stream>>>(
      T, BTwhf, bl_f, (void*)XF, 1024, 512, 512, 0, 0, 2, ea,
      BTwhb, bl_b, (void*)XB, 1024, 8);
  // 3. BiLSTM -> XT cols [0,512)   (HexS overlays dead T; 128 blocks)
  k_lstm6<<<dim3(128), dim3(256), 0, stream>>>(XF, XB, WBf, WBb, HexS, FLG, XT);
  // 5. xWiou / xWf merged (one launch): bx<6 -> XWIOU, bx>=6 -> XWF
  k_mgemm<<<dim3(8, 128), dim3(256), 0, stream>>>(
      XT, BTiou, b_iou, (void*)XWIOU, 768, 544, 544, 0, 0, 0, ea,
      BTf, bf_t, (void*)XWF, 256, 6);
  // 6. tree: leaves, 3 big MFMA stages, then the 5-stage tail in one kernel
  k_leaves<<<dim3(8192), dim3(256), 0, stream>>>(XWIOU, H, C);
  const int plos[3] = {64, 32, 16};
  const int lgs[3]  = {6, 5, 4};
  for (int s = 0; s < 3; ++s) {
    int plo = plos[s], lg = lgs[s];
    int npar = 1 << lg;
    int Mch = 128 * npar;
    int Mp = 64 * npar;
    int nb0 = 2 * npar;                     // FCb: 2 col-blocks x npar rows
    int nb1 = 6 * ((Mp + 127) / 128);       // IOUL: 6 col-blocks x ceil rows
    k_tgemm<<<dim3(nb0 + nb1), dim3(256), 0, stream>>>(
        H, BTuf, FCb, Mch, 2 * plo, lg + 1,
        BTuiou, IOUL, Mp, plo, lg, nb0, heads, XWF, C);
    k_update<<<dim3(Mp), dim3(256), 0, stream>>>(XWIOU, IOUL, FCb, H, C, plo, lg);
  }
  k_tree_tail<<<dim3(64), dim3(256), 0, stream>>>(XWIOU, XWF, heads,
                                                  Uf_t, U_iou, H, C);
  // 7. classifier
  k_classifier<<<dim3(64), dim3(256), 0, stream>>>(H, root, W1, b1, W2, b2,
                                                   (float*)d_out);
}

// Round 19
// 1140.060 us; speedup vs baseline: 2.3717x; 1.0114x over previous
//
#include <hip/hip_runtime.h>
#include <hip/hip_fp16.h>
#include <math.h>

// ---------------------------------------------------------------------------
// RelationExtractionModel B=64,T=256. Round 28: fourth tile-shrink — 256
// blocks = 2 dirs x 16 slices x 8 batch-eighths(8). MFMA stays M=16 (rows
// 8-15 zero, unread); gate/publish/gather on tid<128; publish 256B, gather
// 15x256B. Also removes the post-MFMA barrier (proof: GT reads of step s-1
// complete before its drain-bar; first GT write of step s is after the
// gather-bar of s-1 -> 3 barriers intervene). r2 protocol per (dir,eighth)
// group of 16 blocks (16 independent groups). Everything else = round 27
// (1153us verified).
// ---------------------------------------------------------------------------

typedef _Float16 f16x8 __attribute__((ext_vector_type(8)));
typedef float    f32x4 __attribute__((ext_vector_type(4)));

union PK1 { _Float16 h; unsigned short u16; };

#define LOG2E 1.44269504088896340736f

__device__ __forceinline__ float fexp2(float x) {
  return __builtin_amdgcn_exp2f(x);
}
__device__ __forceinline__ float frcp(float x) {
  return __builtin_amdgcn_rcpf(x);
}
__device__ __forceinline__ float sigm(float x) {
  return frcp(1.0f + fexp2(-LOG2E * x));
}
__device__ __forceinline__ float tanh_fast(float x) {
  return 1.0f - 2.0f * frcp(1.0f + fexp2(2.0f * LOG2E * x));
}

struct EmbArgs {
  const float* tf; const int* pos_ids; const int* dep_ids;
  const int* e1; const int* e2; const int* sdp;
  const float* pos_tab; const float* dep_tab; const float* dist_tab;
  const float* sdp_tab;
};

// ---------------- merged prep: packs + zft + WB packs + flag zero + depfill
// ranges (all multiples of 256; formulas verbatim from proven kernels):
//  BTft 466944 | zft 8192 | BTwhf 524288 | BTwhb 524288 | BTiou 417792 |
//  BTf 139264 | WBf 262144 | WBb 262144 | FLG 65536 | depfill 524288 |
//  BTuf 65536 | BTuiou 196608   -> total 3457024 = 13504 blocks x 256
__global__ __launch_bounds__(256) void k_prep(
    const float* __restrict__ W_ft, __half* __restrict__ BTft,
    const float* __restrict__ Wih_f, __half* __restrict__ BTwhf,
    const float* __restrict__ Wih_b, __half* __restrict__ BTwhb,
    const float* __restrict__ W_iou, __half* __restrict__ BTiou,
    const float* __restrict__ Wf_t, __half* __restrict__ BTf,
    const float* __restrict__ Whh_f, __half* __restrict__ WBf,
    const float* __restrict__ Whh_b, __half* __restrict__ WBb,
    unsigned int* __restrict__ FLG,
    const int* __restrict__ dep_ids, const float* __restrict__ dep_tab,
    __half* __restrict__ XT,
    const float* __restrict__ Uf, __half* __restrict__ BTuf,
    const float* __restrict__ Uiou, __half* __restrict__ BTuiou) {
  int e = blockIdx.x * 256 + threadIdx.x;
  if (e < 466944) {                       // BTft: n fastest (coalesced read)
    int n = e & 511, k = e >> 9;          // k<912
    BTft[(size_t)n * 928 + k] = __float2half_rn(W_ft[(size_t)k * 512 + n]);
  } else if ((e -= 466944) < 8192) {      // zft pad cols [912,928)
    int n = e >> 4, kk = e & 15;
    BTft[(size_t)n * 928 + 912 + kk] = __float2half_rn(0.0f);
  } else if ((e -= 8192) < 524288) {      // BTwhf
    int n = e & 1023, k = e >> 10;        // k<512
    BTwhf[(size_t)n * 512 + k] = __float2half_rn(Wih_f[(size_t)k * 1024 + n]);
  } else if ((e -= 524288) < 524288) {    // BTwhb
    int n = e & 1023, k = e >> 10;
    BTwhb[(size_t)n * 512 + k] = __float2half_rn(Wih_b[(size_t)k * 1024 + n]);
  } else if ((e -= 524288) < 417792) {    // BTiou: N=768, K=544
    int n = e % 768, k = e / 768;
    BTiou[(size_t)n * 544 + k] = __float2half_rn(W_iou[(size_t)k * 768 + n]);
  } else if ((e -= 417792) < 139264) {    // BTf: N=256, K=544
    int n = e & 255, k = e >> 8;
    BTf[(size_t)n * 544 + k] = __float2half_rn(Wf_t[(size_t)k * 256 + n]);
  } else if ((e -= 139264) < 262144) {    // WBf  [r11 k_packWB verbatim]
    int k = e & 255, c = (e >> 8) & 127, j = e >> 15;
    int col = (c & 3) * 256 + j * 32 + (c >> 2);
    WBf[e] = __float2half_rn(Whh_f[(size_t)k * 1024 + col]);
  } else if ((e -= 262144) < 262144) {    // WBb
    int k = e & 255, c = (e >> 8) & 127, j = e >> 15;
    int col = (c & 3) * 256 + j * 32 + (c >> 2);
    WBb[e] = __float2half_rn(Whh_b[(size_t)k * 1024 + col]);
  } else if ((e -= 262144) < 65536) {     // flag zero [dir2][be8][slice16][256]
    FLG[e] = 0u;
  } else if ((e -= 65536) < 524288) {     // depfill -> XT cols [512,544)
    int row = e >> 5, kk = e & 31;
    XT[(size_t)row * 544 + 512 + kk] =
        __float2half_rn(dep_tab[dep_ids[row] * 32 + kk]);
  } else if ((e -= 524288) < 65536) {     // BTuf: N=256, K=256
    int n = e & 255, k = e >> 8;
    BTuf[(size_t)n * 256 + k] = __float2half_rn(Uf[(size_t)k * 256 + n]);
  } else {                                // BTuiou: N=768, K=256
    e -= 65536;
    int n = e % 768, k = e / 768;
    BTuiou[(size_t)n * 256 + k] = __float2half_rn(Uiou[(size_t)k * 768 + n]);
  }
}

// ---------------- MFMA f16 GEMM (dual-job via split_bx) ----------------
// out_mode: 0 = f32 row-major, 1 = f16 row-major, 2 = f16 LSTM staging layout
// [t][slice8][gate4][b64][u32] (M must be 16384 rows = b*256+t, N=1024).
// Blocks with blockIdx.x >= split_bx run the secondary job (BT2/bias2/out2/N2).
__global__ __launch_bounds__(256) void k_mgemm(
    const __half* __restrict__ A16, const __half* __restrict__ BT,
    const float* __restrict__ bias, void* __restrict__ out,
    int N, int K, int lda, int a_embed, int act_tanh, int out_mode,
    EmbArgs ea,
    const __half* __restrict__ BT2, const float* __restrict__ bias2,
    void* __restrict__ out2, int N2, int split_bx) {
  __shared__ _Float16 As[128 * 40];
  __shared__ _Float16 Bs[128 * 40];
  int tid = threadIdx.x;
  int lane = tid & 63, wave = tid >> 6;
  int wm = wave & 1, wn = wave >> 1;
  int bxx = blockIdx.x;
  const __half* BTp = BT; const float* biasp = bias;
  void* outp = out; int Np = N;
  if (bxx >= split_bx) {
    bxx -= split_bx; BTp = BT2; biasp = bias2; outp = out2; Np = N2;
  }
  int col0 = bxx * 128, row0 = blockIdx.y * 128;

  f32x4 acc[4][4];
#pragma unroll
  for (int i = 0; i < 4; ++i)
#pragma unroll
    for (int j = 0; j < 4; ++j) acc[i][j] = (f32x4)0.0f;

  for (int kt = 0; kt < K; kt += 32) {
    __syncthreads();
#pragma unroll
    for (int it = 0; it < 2; ++it) {
      int lin = tid + it * 256;
      int r = lin & 127, kh8 = (lin >> 7) * 8;
      f16x8 va;
      if (!a_embed) {
        va = *(const f16x8*)(A16 + (size_t)(row0 + r) * lda + kt + kh8);
      } else {
        int row = row0 + r;
        int k0 = kt + kh8;
        if (k0 >= 912) {
          va = (f16x8)(_Float16)0.0f;
        } else {
          const float* src;
          if (k0 < 768) {
            src = ea.tf + (size_t)row * 768 + k0;
          } else {
            int b_ = row >> 8, t_ = row & 255;
            if (k0 < 800) src = ea.pos_tab + ea.pos_ids[row] * 32 + (k0 - 768);
            else if (k0 < 832) src = ea.dep_tab + ea.dep_ids[row] * 32 + (k0 - 800);
            else if (k0 < 864) {
              int d = t_ - ea.e1[b_] + 10; d = d < 0 ? 0 : (d > 20 ? 20 : d);
              src = ea.dist_tab + d * 32 + (k0 - 832);
            } else if (k0 < 896) {
              int d = t_ - ea.e2[b_] + 10; d = d < 0 ? 0 : (d > 20 ? 20 : d);
              src = ea.dist_tab + d * 32 + (k0 - 864);
            } else {
              src = ea.sdp_tab + ea.sdp[row] * 16 + (k0 - 896);
            }
          }
          float4 a = *(const float4*)src;
          float4 b2 = *(const float4*)(src + 4);
          va[0] = (_Float16)a.x;  va[1] = (_Float16)a.y;
          va[2] = (_Float16)a.z;  va[3] = (_Float16)a.w;
          va[4] = (_Float16)b2.x; va[5] = (_Float16)b2.y;
          va[6] = (_Float16)b2.z; va[7] = (_Float16)b2.w;
        }
      }
      *(f16x8*)&As[r * 40 + kh8] = va;
      f16x8 vb = *(const f16x8*)(BTp + (size_t)(col0 + r) * K + kt + kh8);
      *(f16x8*)&Bs[r * 40 + kh8] = vb;
    }
    __syncthreads();
    f16x8 af[4], bf[4];
    int kq = (lane >> 4) * 8;
#pragma unroll
    for (int mt = 0; mt < 4; ++mt)
      af[mt] = *(const f16x8*)&As[(wm * 64 + mt * 16 + (lane & 15)) * 40 + kq];
#pragma unroll
    for (int nt = 0; nt < 4; ++nt)
      bf[nt] = *(const f16x8*)&Bs[(wn * 64 + nt * 16 + (lane & 15)) * 40 + kq];
#pragma unroll
    for (int mt = 0; mt < 4; ++mt)
#pragma unroll
      for (int nt = 0; nt < 4; ++nt)
        acc[mt][nt] = __builtin_amdgcn_mfma_f32_16x16x32_f16(
            af[mt], bf[nt], acc[mt][nt], 0, 0, 0);
  }

#pragma unroll
  for (int mt = 0; mt < 4; ++mt) {
#pragma unroll
    for (int nt = 0; nt < 4; ++nt) {
      int col = col0 + wn * 64 + nt * 16 + (lane & 15);
      float bv = biasp[col];
#pragma unroll
      for (int r = 0; r < 4; ++r) {
        int row = row0 + wm * 64 + mt * 16 + (lane >> 4) * 4 + r;
        float v = acc[mt][nt][r] + bv;
        if (act_tanh) v = tanh_fast(v);
        if (out_mode == 0) {
          ((float*)outp)[(size_t)row * Np + col] = v;
        } else if (out_mode == 1) {
          ((__half*)outp)[(size_t)row * Np + col] = __float2half_rn(v);
        } else {
          // LSTM staging: [t][slice8][gate4][b][32 units]
          int b_ = row >> 8, t_ = row & 255;
          int g_ = col >> 8, u_ = col & 255;
          int sl = u_ >> 5, ul = u_ & 31;
          ((__half*)outp)[((((size_t)(t_ * 8 + sl) * 4 + g_) * 64 + b_) * 32) + ul] =
              __float2half_rn(v);
        }
      }
    }
  }
}

// ---------------- BiLSTM v18: 256 blocks = 2 dir x 16 slice x 8 eighth ----
// 16 units/slice, 8 batches/block. r2 protocol per (dir,eighth) group of 16
// blocks (16 independent groups). 8 MFMA/wave (M=16 tile; rows 8-15 zero,
// unread). Gate/publish/gather on tid<128. 4 barriers/step (post-MFMA
// barrier proven redundant). Busy-poll, xW prefetch under the rendezvous.
__global__ __launch_bounds__(256, 1) void k_lstm7(
    const __half* __restrict__ XFs, const __half* __restrict__ XBs,
    const __half* __restrict__ WBf, const __half* __restrict__ WBb,
    __half* __restrict__ HexS, unsigned int* __restrict__ flags,
    __half* __restrict__ XT) {
  int bx = blockIdx.x;          // 0..255
  int dir = bx >> 7, slice = (bx >> 3) & 15, be = bx & 7;
  int tid = threadIdx.x;
  int lane = tid & 63, wave = tid >> 6;
  const __half* xWs = dir ? XBs : XFs;
  const __half* WB = dir ? WBb : WBf;
  __half* hexd = HexS + (size_t)dir * 256 * 16384;  // [step][be8][sl16][b8][u16]
  unsigned int* flg = flags + (dir * 8 + be) * 4096;  // [slice16][step256]

  __shared__ _Float16 H[16 * 266];   // [b16][u]; rows 8-15 stay zero
  __shared__ float GT[16 * 69];      // [b16][c64], row stride 69 dw

  // ---- preload B-fragments: 64 cols x 256 k (32 VGPRs)  [r22 formula]
  f16x8 bfrag[8];
  {
    int c = (slice & 1) * 64 + wave * 16 + (lane & 15);
#pragma unroll
    for (int kt = 0; kt < 8; ++kt)
      bfrag[kt] = *(const f16x8*)(
          WB + ((size_t)((slice >> 1) * 128 + c) * 256) + kt * 32 +
          (lane >> 4) * 8);
  }
  // ---- zero H (rows 8-15 remain zero for the whole kernel)
  for (int i = tid; i < 16 * 266 / 8; i += 256)
    ((f16x8*)H)[i] = (f16x8)(_Float16)0.0f;
  float cst = 0.0f;
  int b_own = tid >> 4;   // 0..15; valid batches are 0..7
  int uc = tid & 15;      // single unit within the 16-unit slice
  bool valid = (b_own < 8);
  int bglob = be * 8 + b_own;  // 0..63 when valid
  size_t xw_off = (size_t)bglob * 32 + (slice & 1) * 16 + uc;
  // ---- preload xW gates for step 0 (valid threads only)
  float xwg[4] = {0.0f, 0.0f, 0.0f, 0.0f};
  if (valid) {
    int t0 = dir ? 255 : 0;
    const __half* xwp = xWs + ((size_t)(t0 * 8 + (slice >> 1)) * 8192) + xw_off;
#pragma unroll
    for (int g = 0; g < 4; ++g) xwg[g] = __half2float(xwp[g * 2048]);
  }
  __syncthreads();

  for (int s = 0; s < 256; ++s) {
    int t = dir ? (255 - s) : s;

    // ---- MFMA: gates[16 b, 64 c] = H[16,256] @ Wslice[256,64]
    f32x4 acc = (f32x4)0.0f;
#pragma unroll
    for (int kt = 0; kt < 8; ++kt) {
      f16x8 a = *(const f16x8*)&H[(lane & 15) * 266 + kt * 32 +
                                  (lane >> 4) * 8];
      acc = __builtin_amdgcn_mfma_f32_16x16x32_f16(a, bfrag[kt], acc, 0, 0, 0);
    }
    // (post-MFMA barrier removed: GT reads of step s-1 completed before that
    //  step's drain-bar; 3 barriers separate them from this write)
    // ---- transpose C-layout -> GT[b16][c64]  (mt=0 formula)
    {
      int col = wave * 16 + (lane & 15);
#pragma unroll
      for (int r = 0; r < 4; ++r) {
        int b = (lane >> 4) * 4 + r;
        GT[b * 69 + col] = acc[r];
      }
    }
    __syncthreads();  // GT visible; H MFMA reads done
    // ---- c/h update for own (b_own<8, unit uc)
    PK1 hv; hv.u16 = 0;
    if (valid) {
      float4 g4 = *(const float4*)&GT[b_own * 69 + 4 * uc];
      float gi = g4.x + xwg[0];
      float gf = g4.y + xwg[1];
      float gg = g4.z + xwg[2];
      float go = g4.w + xwg[3];
      cst = sigm(gf) * cst + sigm(gi) * tanh_fast(gg);
      float hn = sigm(go) * tanh_fast(cst);
      hv.h = (_Float16)hn;
      // own h -> LDS H (unit slice*16 + uc)
      H[b_own * 266 + slice * 16 + uc] = hv.h;
    }

    if (s < 255) {
      __half* hexq = hexd + (size_t)s * 16384;
      // ---- publish directly from registers (block-contiguous 256B)
      if (valid) {
        unsigned short* dst =
            (unsigned short*)(hexq + (be * 16 + slice) * 128 + tid);
        __hip_atomic_store(dst, hv.u16, __ATOMIC_RELAXED,
                           __HIP_MEMORY_SCOPE_AGENT);
      }
      // drain own wave's publish stores to the LLC, then block rendezvous
      asm volatile("s_waitcnt vmcnt(0)" ::: "memory");
      __syncthreads();
      if (tid == 0)
        __hip_atomic_store(&flg[(slice << 8) + s], 1u, __ATOMIC_RELAXED,
                           __HIP_MEMORY_SCOPE_AGENT);
      // XT store AFTER flag (out of the drain path)
      if (valid)
        XT[(size_t)((bglob << 8) + t) * 544 + dir * 256 + slice * 16 + uc] =
            *(__half*)&hv.h;
      // ---- prefetch next step's xW gates (latency hides under poll+gather)
      float xwn[4] = {0.0f, 0.0f, 0.0f, 0.0f};
      if (valid) {
        int tn = dir ? (254 - s) : (s + 1);
        const __half* xwp =
            xWs + ((size_t)(tn * 8 + (slice >> 1)) * 8192) + xw_off;
#pragma unroll
        for (int g = 0; g < 4; ++g) xwn[g] = __half2float(xwp[g * 2048]);
      }
      // poll the 15 peer flags in parallel (lanes 0..15); load RT paces loop
      if (tid < 16 && tid != slice) {
        while (__hip_atomic_load(&flg[(tid << 8) + s], __ATOMIC_RELAXED,
                                 __HIP_MEMORY_SCOPE_AGENT) == 0u) {}
      }
      __syncthreads();
      // ---- gather 15 peer slices for THIS eighth (step-unique, MLP)
      if (valid) {
#pragma unroll
        for (int i = 0; i < 15; ++i) {
          int ps = i + (i >= slice ? 1 : 0);
          __half pv = hexq[(be * 16 + ps) * 128 + tid];
          H[b_own * 266 + ps * 16 + uc] = *(_Float16*)&pv;
        }
      }
      __syncthreads();  // H complete before next step's MFMA
#pragma unroll
      for (int g = 0; g < 4; ++g) xwg[g] = xwn[g];
    } else {
      if (valid)
        XT[(size_t)((bglob << 8) + t) * 544 + dir * 256 + slice * 16 + uc] =
            *(__half*)&hv.h;
    }
  }
}

// ---------------- MFMA f16 dual-job tree GEMM (stages 0-2 only) ----------
__global__ __launch_bounds__(256) void k_tgemm(
    const float* __restrict__ A,
    const __half* __restrict__ BT0, float* __restrict__ Cv0, int M0,
    int band_lo0, int blog0,
    const __half* __restrict__ BT1, float* __restrict__ Cv1, int M1,
    int band_lo1, int blog1, int nb0,
    const int* __restrict__ dep_heads,
    const float* __restrict__ xWf, const float* __restrict__ c_buf) {
  __shared__ _Float16 As[128 * 40];
  __shared__ _Float16 Bs[128 * 40];
  int tid = threadIdx.x;
  int lane = tid & 63, wave = tid >> 6;
  int wm = wave & 1, wn = wave >> 1;
  int f = blockIdx.x;
  const __half* BT; float* Cv; int M, N, band_lo, blog, amode, epi;
  int bx, by;
  if (f < nb0) {
    BT = BT0; Cv = Cv0; M = M0; N = 256; band_lo = band_lo0; blog = blog0;
    amode = 1; epi = 2; bx = f & 1; by = f >> 1;
  } else {
    f -= nb0;
    BT = BT1; Cv = Cv1; M = M1; N = 768; band_lo = band_lo1; blog = blog1;
    amode = 2; epi = 0; bx = f % 6; by = f / 6;
  }
  int col0 = bx * 128, row0 = by * 128;
  int bmask = (1 << blog) - 1;

  f32x4 acc[4][4];
#pragma unroll
  for (int i = 0; i < 4; ++i)
#pragma unroll
    for (int j = 0; j < 4; ++j) acc[i][j] = (f32x4)0.0f;

  for (int kt = 0; kt < 256; kt += 32) {
    __syncthreads();
#pragma unroll
    for (int it = 0; it < 2; ++it) {
      int lin = tid + it * 256;
      int r = lin & 127, kh8 = (lin >> 7) * 8;
      int row = row0 + r;
      f16x8 va = (f16x8)(_Float16)0.0f;
      if (row < M) {
        if (amode == 1) {
          int b_ = row >> blog, t_ = band_lo + (row & bmask);
          const float* src = A + (size_t)((b_ << 8) + t_) * 256 + kt + kh8;
          float4 a4 = *(const float4*)src;
          float4 b4 = *(const float4*)(src + 4);
          va[0] = (_Float16)a4.x; va[1] = (_Float16)a4.y;
          va[2] = (_Float16)a4.z; va[3] = (_Float16)a4.w;
          va[4] = (_Float16)b4.x; va[5] = (_Float16)b4.y;
          va[6] = (_Float16)b4.z; va[7] = (_Float16)b4.w;
        } else {
          int b_ = row >> blog, p_ = band_lo + (row & bmask);
          const float* p0 = A + (size_t)((b_ << 8) + 2 * p_) * 256 + kt + kh8;
          float4 x0a = {0.0f, 0.0f, 0.0f, 0.0f};
          float4 x0b = {0.0f, 0.0f, 0.0f, 0.0f};
          if (2 * p_ != 0) {
            x0a = *(const float4*)p0;
            x0b = *(const float4*)(p0 + 4);
          }
          float4 x1a = *(const float4*)(p0 + 256);
          float4 x1b = *(const float4*)(p0 + 260);
          va[0] = (_Float16)(x0a.x + x1a.x); va[1] = (_Float16)(x0a.y + x1a.y);
          va[2] = (_Float16)(x0a.z + x1a.z); va[3] = (_Float16)(x0a.w + x1a.w);
          va[4] = (_Float16)(x0b.x + x1b.x); va[5] = (_Float16)(x0b.y + x1b.y);
          va[6] = (_Float16)(x0b.z + x1b.z); va[7] = (_Float16)(x0b.w + x1b.w);
        }
      }
      *(f16x8*)&As[r * 40 + kh8] = va;
      f16x8 vb = *(const f16x8*)(BT + (size_t)(col0 + r) * 256 + kt + kh8);
      *(f16x8*)&Bs[r * 40 + kh8] = vb;
    }
    __syncthreads();
    f16x8 af[4], bf[4];
    int kq = (lane >> 4) * 8;
#pragma unroll
    for (int mt = 0; mt < 4; ++mt)
      af[mt] = *(const f16x8*)&As[(wm * 64 + mt * 16 + (lane & 15)) * 40 + kq];
#pragma unroll
    for (int nt = 0; nt < 4; ++nt)
      bf[nt] = *(const f16x8*)&Bs[(wn * 64 + nt * 16 + (lane & 15)) * 40 + kq];
#pragma unroll
    for (int mt = 0; mt < 4; ++mt)
#pragma unroll
      for (int nt = 0; nt < 4; ++nt)
        acc[mt][nt] = __builtin_amdgcn_mfma_f32_16x16x32_f16(
            af[mt], bf[nt], acc[mt][nt], 0, 0, 0);
  }

#pragma unroll
  for (int mt = 0; mt < 4; ++mt) {
#pragma unroll
    for (int nt = 0; nt < 4; ++nt) {
      int col = col0 + wn * 64 + nt * 16 + (lane & 15);
#pragma unroll
      for (int r = 0; r < 4; ++r) {
        int row = row0 + wm * 64 + mt * 16 + (lane >> 4) * 4 + r;
        if (row >= M) continue;
        float v = acc[mt][nt][r];
        if (epi == 2) {
          int b_ = row >> blog, t_ = band_lo + (row & bmask);
          int par = dep_heads[(b_ << 8) + t_];
          float m = (par != t_) ? 1.0f : 0.0f;
          float xwv = xWf[(size_t)((b_ << 8) + par) * 256 + col];
          float cv = c_buf[(size_t)((b_ << 8) + t_) * 256 + col];
          v = sigm(v + xwv) * cv * m;
        }
        Cv[(size_t)row * N + col] = v;
      }
    }
  }
}

// ---------------- tree tail level: compile-time bounds (registers!) ------
template <int PLO, int NP>
__device__ __forceinline__ void tree_level(
    int b, int j, float* __restrict__ Hs, float* __restrict__ Cs,
    const float* __restrict__ xWiou, const float* __restrict__ xWf,
    const int* __restrict__ dep_heads,
    const float* __restrict__ Uf, const float* __restrict__ Uiou) {
  constexpr int NCH = 2 * NP;
  constexpr int C0 = 2 * PLO;
  float fd[NCH];
#pragma unroll
  for (int ci = 0; ci < NCH; ++ci) fd[ci] = 0.0f;
  for (int k = 0; k < 256; ++k) {
    float u = Uf[(size_t)k * 256 + j];
#pragma unroll
    for (int ci = 0; ci < NCH; ++ci)
      fd[ci] += Hs[(C0 + ci) * 256 + k] * u;
  }
  float io0[NP], io1[NP], io2[NP];
#pragma unroll
  for (int p = 0; p < NP; ++p) { io0[p] = 0.0f; io1[p] = 0.0f; io2[p] = 0.0f; }
  for (int k = 0; k < 256; ++k) {
    float u0 = Uiou[(size_t)k * 768 + j];
    float u1 = Uiou[(size_t)k * 768 + 256 + j];
    float u2 = Uiou[(size_t)k * 768 + 512 + j];
#pragma unroll
    for (int p = 0; p < NP; ++p) {
      constexpr bool has0 = (PLO != 0);
      int pp = PLO + p;
      float hs = Hs[(2 * pp + 1) * 256 + k];
      if (has0 || p > 0) hs += Hs[2 * pp * 256 + k];
      io0[p] += hs * u0; io1[p] += hs * u1; io2[p] += hs * u2;
    }
  }
  __syncthreads();  // all dot reads complete before parent-row writes
#pragma unroll
  for (int p = 0; p < NP; ++p) {
    int pp = PLO + p;
    size_t prow = (size_t)((b << 8) + pp);
    int ta = 2 * pp, tb = 2 * pp + 1;
    int para = dep_heads[(b << 8) + ta];
    int parb = dep_heads[(b << 8) + tb];
    float ma = (para != ta) ? 1.0f : 0.0f;
    float mb = (parb != tb) ? 1.0f : 0.0f;
    float fca = sigm(fd[2 * p] + xWf[(size_t)((b << 8) + para) * 256 + j]) *
                Cs[ta * 256 + j] * ma;
    float fcb = sigm(fd[2 * p + 1] + xWf[(size_t)((b << 8) + parb) * 256 + j]) *
                Cs[tb * 256 + j] * mb;
    float fcsum = fca + fcb;
    float iv = xWiou[prow * 768 + j] + io0[p];
    float ov = xWiou[prow * 768 + 256 + j] + io1[p];
    float uv = xWiou[prow * 768 + 512 + j] + io2[p];
    float cc = sigm(iv) * tanh_fast(uv) + fcsum;
    float hh = sigm(ov) * tanh_fast(cc);
    Cs[pp * 256 + j] = cc;
    Hs[pp * 256 + j] = hh;
  }
  __syncthreads();
}

// ---------------- tree tail: stages plo 8,4,2,1,0 in ONE kernel ----------
__global__ __launch_bounds__(256) void k_tree_tail(
    const float* __restrict__ xWiou, const float* __restrict__ xWf,
    const int* __restrict__ dep_heads,
    const float* __restrict__ Uf, const float* __restrict__ Uiou,
    float* __restrict__ h_buf, float* __restrict__ c_buf) {
  int b = blockIdx.x, j = threadIdx.x;
  __shared__ float Hs[32 * 256];
  __shared__ float Cs[32 * 256];
  for (int t = 0; t < 16; ++t) {
    Hs[t * 256 + j] = 0.0f;
    Cs[t * 256 + j] = 0.0f;
  }
  for (int t = 16; t < 32; ++t) {
    size_t row = (size_t)((b << 8) + t);
    Hs[t * 256 + j] = h_buf[row * 256 + j];
    Cs[t * 256 + j] = c_buf[row * 256 + j];
  }
  __syncthreads();
  tree_level<8, 8>(b, j, Hs, Cs, xWiou, xWf, dep_heads, Uf, Uiou);
  tree_level<4, 4>(b, j, Hs, Cs, xWiou, xWf, dep_heads, Uf, Uiou);
  tree_level<2, 2>(b, j, Hs, Cs, xWiou, xWf, dep_heads, Uf, Uiou);
  tree_level<1, 1>(b, j, Hs, Cs, xWiou, xWf, dep_heads, Uf, Uiou);
  tree_level<0, 1>(b, j, Hs, Cs, xWiou, xWf, dep_heads, Uf, Uiou);
  // write back h rows 0..15 (classifier may read any root index)
  for (int t = 0; t < 16; ++t)
    h_buf[(size_t)((b << 8) + t) * 256 + j] = Hs[t * 256 + j];
}

// ---------------- tree leaves: t in [128,256) ----------------
__global__ __launch_bounds__(256) void k_leaves(
    const float* __restrict__ xWiou, float* __restrict__ h_buf,
    float* __restrict__ c_buf) {
  int r = blockIdx.x;  // 0..8191
  int b = r >> 7, t = 128 + (r & 127);
  size_t row = (size_t)((b << 8) + t);
  int j = threadIdx.x;
  float i = xWiou[row * 768 + j];
  float o = xWiou[row * 768 + 256 + j];
  float u = xWiou[row * 768 + 512 + j];
  float c = sigm(i) * tanh_fast(u);
  float h = sigm(o) * tanh_fast(c);
  c_buf[row * 256 + j] = c;
  h_buf[row * 256 + j] = h;
}

// ---------------- tree stage update (stages 0-2 only) ----------------
__global__ __launch_bounds__(256) void k_update(
    const float* __restrict__ xWiou, const float* __restrict__ iou_lin,
    const float* __restrict__ FC, float* __restrict__ h_buf,
    float* __restrict__ c_buf, int plo, int nplog2) {
  int r = blockIdx.x, j = threadIdx.x;
  int npm = (1 << nplog2) - 1;
  int b = r >> nplog2, loc = r & npm, p = plo + loc;
  size_t row = (size_t)((b << 8) + p);
  float i = xWiou[row * 768 + j] + iou_lin[(size_t)r * 768 + j];
  float o = xWiou[row * 768 + 256 + j] + iou_lin[(size_t)r * 768 + 256 + j];
  float u = xWiou[row * 768 + 512 + j] + iou_lin[(size_t)r * 768 + 512 + j];
  int nch = 2 << nplog2;
  float fc = FC[(size_t)(b * nch + 2 * loc) * 256 + j] +
             FC[(size_t)(b * nch + 2 * loc + 1) * 256 + j];
  float c = sigm(i) * tanh_fast(u) + fc;
  float h = sigm(o) * tanh_fast(c);
  c_buf[row * 256 + j] = c;
  h_buf[row * 256 + j] = h;
}

// ---------------- classifier ----------------
__global__ __launch_bounds__(256) void k_classifier(
    const float* __restrict__ h_buf, const int* __restrict__ root_idx,
    const float* __restrict__ W1, const float* __restrict__ b1,
    const float* __restrict__ W2, const float* __restrict__ b2,
    float* __restrict__ out) {
  int b = blockIdx.x, j = threadIdx.x;
  __shared__ float hroot[256];
  __shared__ float hid[256];
  int root = root_idx[b];
  hroot[j] = h_buf[(size_t)((b << 8) + root) * 256 + j];
  __syncthreads();
  float acc = b1[j];
  for (int k = 0; k < 256; ++k) acc += hroot[k] * W1[k * 256 + j];
  hid[j] = fmaxf(acc, 0.0f);
  __syncthreads();
  if (j < 10) {
    float o = b2[j];
    for (int k = 0; k < 256; ++k) o += hid[k] * W2[k * 10 + j];
    out[b * 10 + j] = o;
  }
}

// ---------------------------------------------------------------------------
extern "C" void kernel_launch(void* const* d_in, const int* in_sizes, int n_in,
                              void* d_out, int out_size, void* d_ws,
                              size_t ws_size, hipStream_t stream) {
  (void)in_sizes; (void)n_in; (void)out_size; (void)ws_size;
  const float* tf       = (const float*)d_in[0];
  const int*   pos_ids  = (const int*)d_in[1];
  const int*   dep_ids  = (const int*)d_in[2];
  const int*   e1       = (const int*)d_in[3];
  const int*   e2       = (const int*)d_in[4];
  const int*   sdp      = (const int*)d_in[5];
  const int*   heads    = (const int*)d_in[6];
  const int*   root     = (const int*)d_in[7];
  const float* pos_tab  = (const float*)d_in[8];
  const float* dep_tab  = (const float*)d_in[9];
  const float* dist_tab = (const float*)d_in[10];
  const float* sdp_tab  = (const float*)d_in[11];
  const float* W_ft     = (const float*)d_in[12];
  const float* b_ft     = (const float*)d_in[13];
  const float* Wih_f    = (const float*)d_in[14];
  const float* Whh_f    = (const float*)d_in[15];
  const float* bl_f     = (const float*)d_in[16];
  const float* Wih_b    = (const float*)d_in[17];
  const float* Whh_b    = (const float*)d_in[18];
  const float* bl_b     = (const float*)d_in[19];
  const float* W_iou    = (const float*)d_in[20];
  const float* U_iou    = (const float*)d_in[21];
  const float* b_iou    = (const float*)d_in[22];
  const float* Wf_t     = (const float*)d_in[23];
  const float* Uf_t     = (const float*)d_in[24];
  const float* bf_t     = (const float*)d_in[25];
  const float* W1       = (const float*)d_in[26];
  const float* b1       = (const float*)d_in[27];
  const float* W2       = (const float*)d_in[28];
  const float* b2       = (const float*)d_in[29];

  // ---- workspace (lifetime-overlaid; peak 122.16 MB < proven-safe 122.7 MB)
  char* ws = (char*)d_ws;
  __half* XF    = (__half*)(ws + 0ull);            // 33.5MB  phase2->3 (staged layout)
  __half* XB    = (__half*)(ws + 33554432ull);     // 33.5MB  phase2->3 (staged layout)
  float*  XWIOU = (float*)(ws + 0ull);             // 50.3MB  phase5->6
  float*  XWF   = (float*)(ws + 50331648ull);      // 16.8MB  phase5->6
  __half* XT    = (__half*)(ws + 67108864ull);     // 17.8MB  phase3->5
  float*  FCb   = (float*)(ws + 67108864ull);      //  8.4MB  phase6
  float*  IOUL  = (float*)(ws + 75497472ull);      // 12.6MB  phase6
  float*  H     = (float*)(ws + 88080384ull);      // 16.8MB  phase6
  __half* T     = (__half*)(ws + 88080384ull);     // 16.8MB  phase1->2 (over H)
  __half* HexS  = (__half*)(ws + 88080384ull);     // 16.8MB  phase3 (over T/H)
  float*  C     = (float*)(ws + 104857600ull);     // 16.8MB  phase6 -> 121634816
  // packs live inside C region (dead before C written):
  __half* BTft  = (__half*)(ws + 104857600ull);    // 950,272
  __half* BTwhf = (__half*)(ws + 105807872ull);    // 1,048,576
  __half* BTwhb = (__half*)(ws + 106856448ull);    // 1,048,576
  __half* BTiou = (__half*)(ws + 107905024ull);    // 835,584
  __half* BTf   = (__half*)(ws + 108740608ull);    // 278,528
  __half* WBf   = (__half*)(ws + 109019136ull);    // 524,288
  __half* WBb   = (__half*)(ws + 109543424ull);    // 524,288
  unsigned int* FLG = (unsigned int*)(ws + 110198784ull);  // 262,144 (2x8x16x256)
  // tree packs (live through phase 6) placed AFTER C:
  __half* BTuiou = (__half*)(ws + 121634816ull);   // 393,216
  __half* BTuf   = (__half*)(ws + 122028032ull);   // 131,072 -> 122159104

  EmbArgs ea{tf, pos_ids, dep_ids, e1, e2, sdp, pos_tab, dep_tab, dist_tab, sdp_tab};

  // 0. merged prep: packs + zft + WB packs + flag zero + depfill + tree packs
  k_prep<<<dim3(13504), dim3(256), 0, stream>>>(
      W_ft, BTft, Wih_f, BTwhf, Wih_b, BTwhb, W_iou, BTiou, Wf_t, BTf,
      Whh_f, WBf, Whh_b, WBb, FLG, dep_ids, dep_tab, XT,
      Uf_t, BTuf, U_iou, BTuiou);

  // 1. T = tanh(embed @ W_ft + b_ft)  [f16 out, embed fused]
  k_mgemm<<<dim3(4, 128), dim3(256), 0, stream>>>(
      nullptr, BTft, b_ft, (void*)T, 512, 928, 0, 1, 1, 1, ea,
      BTft, b_ft, (void*)T, 512, 10000);
  // 2. xW_f / xW_b merged (one launch): bx<8 -> XF job, bx>=8 -> XB job
  k_mgemm<<<dim3(16, 128), dim3(256), 0, stream>>>(
      T, BTwhf, bl_f, (void*)XF, 1024, 512, 512, 0, 0, 2, ea,
      BTwhb, bl_b, (void*)XB, 1024, 8);
  // 3. BiLSTM -> XT cols [0,512)   (HexS overlays dead T; 256 blocks)
  k_lstm7<<<dim3(256), dim3(256), 0, stream>>>(XF, XB, WBf, WBb, HexS, FLG, XT);
  // 5. xWiou / xWf merged (one launch): bx<6 -> XWIOU, bx>=6 -> XWF
  k_mgemm<<<dim3(8, 128), dim3(256), 0, stream>>>(
      XT, BTiou, b_iou, (void*)XWIOU, 768, 544, 544, 0, 0, 0, ea,
      BTf, bf_t, (void*)XWF, 256, 6);
  // 6. tree: leaves, 3 big MFMA stages, then the 5-stage tail in one kernel
  k_leaves<<<dim3(8192), dim3(256), 0, stream>>>(XWIOU, H, C);
  const int plos[3] = {64, 32, 16};
  const int lgs[3]  = {6, 5, 4};
  for (int s = 0; s < 3; ++s) {
    int plo = plos[s], lg = lgs[s];
    int npar = 1 << lg;
    int Mch = 128 * npar;
    int Mp = 64 * npar;
    int nb0 = 2 * npar;                     // FCb: 2 col-blocks x npar rows
    int nb1 = 6 * ((Mp + 127) / 128);       // IOUL: 6 col-blocks x ceil rows
    k_tgemm<<<dim3(nb0 + nb1), dim3(256), 0, stream>>>(
        H, BTuf, FCb, Mch, 2 * plo, lg + 1,
        BTuiou, IOUL, Mp, plo, lg, nb0, heads, XWF, C);
    k_update<<<dim3(Mp), dim3(256), 0, stream>>>(XWIOU, IOUL, FCb, H, C, plo, lg);
  }
  k_tree_tail<<<dim3(64), dim3(256), 0, stream>>>(XWIOU, XWF, heads,
                                                  Uf_t, U_iou, H, C);
  // 7. classifier
  k_classifier<<<dim3(64), dim3(256), 0, stream>>>(H, root, W1, b1, W2, b2,
                                                   (float*)d_out);
}